// Round 1
// baseline (395.652 us; speedup 1.0000x reference)
//
#include <hip/hip_runtime.h>
#include <hip/hip_bf16.h>

// ---------- helpers ----------
typedef __attribute__((ext_vector_type(8))) short bf16x8;
typedef __attribute__((ext_vector_type(4))) float f32x4;
typedef __attribute__((ext_vector_type(4))) unsigned short us4;

__device__ __forceinline__ unsigned short bf16_rne(float f) {
  unsigned u = __float_as_uint(f);
  unsigned r = u + 0x7fffu + ((u >> 16) & 1u);
  return (unsigned short)(r >> 16);
}

__device__ __forceinline__ void gload16(const void* g, void* l) {
  typedef const __attribute__((address_space(1))) unsigned int* gas;
  typedef __attribute__((address_space(3))) unsigned int* las;
  __builtin_amdgcn_global_load_lds((gas)g, (las)l, 16, 0, 0);
}

__device__ __forceinline__ float lane_f(float v, int l) {
  return __int_as_float(__builtin_amdgcn_readlane(__float_as_int(v), l));
}

// ---------- cast inputs (support+query) f32 -> bf16, flat [24576][1024] ----------
__global__ __launch_bounds__(256) void castx(const float* __restrict__ sup,
                                             const float* __restrict__ qry,
                                             unsigned short* __restrict__ X) {
  const int stride = gridDim.x * blockDim.x;
  for (int i = blockIdx.x * blockDim.x + threadIdx.x; i < 6291456; i += stride) {
    float4 v = (i < 2097152) ? ((const float4*)sup)[i] : ((const float4*)qry)[i - 2097152];
    us4 o = { bf16_rne(v.x), bf16_rne(v.y), bf16_rne(v.z), bf16_rne(v.w) };
    *(us4*)(X + (size_t)i * 4) = o;
  }
}

// ---------- transpose+cast W [R][C] f32 -> WT [C][R] bf16 ----------
__global__ __launch_bounds__(256) void transcast(const float* __restrict__ src,
                                                 unsigned short* __restrict__ dst,
                                                 int R, int C) {
  __shared__ float t[32][33];
  const int tx = threadIdx.x & 31, ty = threadIdx.x >> 5;  // ty 0..7
  const int c0 = blockIdx.x * 32, r0 = blockIdx.y * 32;
#pragma unroll
  for (int j = 0; j < 4; j++)
    t[ty + j * 8][tx] = src[(size_t)(r0 + ty + j * 8) * C + c0 + tx];
  __syncthreads();
#pragma unroll
  for (int j = 0; j < 4; j++)
    dst[(size_t)(c0 + ty + j * 8) * R + r0 + tx] = bf16_rne(t[tx][ty + j * 8]);
}

// ---------- bf16 GEMM: C = act(A[M][K] * BT[N][K]^T + bias) ----------
template <int ACT, int OUTBF>
__global__ __launch_bounds__(256) void gemm_bt(const unsigned short* __restrict__ A,
                                               const unsigned short* __restrict__ BT,
                                               const float* __restrict__ bias,
                                               void* __restrict__ Cout,
                                               int M, int N, int K) {
  __shared__ __attribute__((aligned(16))) unsigned short lA[128 * 32];
  __shared__ __attribute__((aligned(16))) unsigned short lB[128 * 32];
  const int tid = threadIdx.x, lane = tid & 63, wid = tid >> 6;
  const int wm = wid >> 1, wn = wid & 1;
  const int m0 = blockIdx.y * 128, n0 = blockIdx.x * 128;
  const int l15 = lane & 15, lg = lane >> 4;

  f32x4 acc[4][4] = {};
  const size_t ldab = (size_t)K * 2;
  const char* Ab = (const char*)A;
  const char* Bb = (const char*)BT;
  char* lAc = (char*)lA;
  char* lBc = (char*)lB;
  const int soff = wid * 2048 + lane * 16;

  for (int k0 = 0; k0 < K; k0 += 32) {
    __syncthreads();
#pragma unroll
    for (int c = 0; c < 2; ++c) {
      int off = soff + c * 1024;
      int row = off >> 6, ib = off & 63;
      gload16(Ab + (size_t)(m0 + row) * ldab + k0 * 2 + ib, lAc + wid * 2048 + c * 1024);
      gload16(Bb + (size_t)(n0 + row) * ldab + k0 * 2 + ib, lBc + wid * 2048 + c * 1024);
    }
    __syncthreads();
    bf16x8 af[4], bfr[4];
#pragma unroll
    for (int m = 0; m < 4; m++)
      af[m] = *(const bf16x8*)(lAc + ((wm * 64 + m * 16 + l15) * 64 + lg * 16));
#pragma unroll
    for (int n = 0; n < 4; n++)
      bfr[n] = *(const bf16x8*)(lBc + ((wn * 64 + n * 16 + l15) * 64 + lg * 16));
#pragma unroll
    for (int m = 0; m < 4; m++)
#pragma unroll
      for (int n = 0; n < 4; n++)
        acc[m][n] = __builtin_amdgcn_mfma_f32_16x16x32_bf16(af[m], bfr[n], acc[m][n], 0, 0, 0);
  }

  float bv[4];
#pragma unroll
  for (int n = 0; n < 4; n++) bv[n] = bias[n0 + wn * 64 + n * 16 + l15];
#pragma unroll
  for (int m = 0; m < 4; m++) {
    int rbase = m0 + wm * 64 + m * 16 + lg * 4;
#pragma unroll
    for (int n = 0; n < 4; n++) {
      int col = n0 + wn * 64 + n * 16 + l15;
#pragma unroll
      for (int j = 0; j < 4; j++) {
        float v = acc[m][n][j] + bv[n];
        if (ACT) v = v > 0.f ? v : 0.f;
        size_t idx = (size_t)(rbase + j) * N + col;
        if (OUTBF) ((unsigned short*)Cout)[idx] = bf16_rne(v);
        else       ((float*)Cout)[idx] = v;
      }
    }
  }
}

// ---------- per-task K = Es Es^T + eps*I, eta2 = log2(e)/(2*max row abs-sum) ----------
__global__ __launch_bounds__(256) void makeK(const float* __restrict__ E,
                                             float* __restrict__ Km,
                                             float* __restrict__ eta2v) {
  __shared__ float es[32][512];  // 64 KB exactly
  const int b = blockIdx.x, tid = threadIdx.x;
  const float4* Eb = (const float4*)(E + (size_t)b * 32 * 512);
  float4* es4 = (float4*)&es[0][0];
  for (int i = tid; i < 32 * 128; i += 256) es4[i] = Eb[i];
  __syncthreads();

  const int s = tid >> 3, tq = tid & 7;
  const float4* rs4 = (const float4*)&es[s][0];
  const float4* rt0 = (const float4*)&es[tq * 4 + 0][0];
  const float4* rt1 = (const float4*)&es[tq * 4 + 1][0];
  const float4* rt2 = (const float4*)&es[tq * 4 + 2][0];
  const float4* rt3 = (const float4*)&es[tq * 4 + 3][0];
  float4 a0 = {0, 0, 0, 0}, a1 = {0, 0, 0, 0}, a2 = {0, 0, 0, 0}, a3 = {0, 0, 0, 0};
  for (int dd = 0; dd < 128; ++dd) {
    float4 av = rs4[dd];
    float4 b0 = rt0[dd], b1 = rt1[dd], b2 = rt2[dd], b3 = rt3[dd];
    a0.x = fmaf(av.x, b0.x, a0.x); a0.y = fmaf(av.y, b0.y, a0.y);
    a0.z = fmaf(av.z, b0.z, a0.z); a0.w = fmaf(av.w, b0.w, a0.w);
    a1.x = fmaf(av.x, b1.x, a1.x); a1.y = fmaf(av.y, b1.y, a1.y);
    a1.z = fmaf(av.z, b1.z, a1.z); a1.w = fmaf(av.w, b1.w, a1.w);
    a2.x = fmaf(av.x, b2.x, a2.x); a2.y = fmaf(av.y, b2.y, a2.y);
    a2.z = fmaf(av.z, b2.z, a2.z); a2.w = fmaf(av.w, b2.w, a2.w);
    a3.x = fmaf(av.x, b3.x, a3.x); a3.y = fmaf(av.y, b3.y, a3.y);
    a3.z = fmaf(av.z, b3.z, a3.z); a3.w = fmaf(av.w, b3.w, a3.w);
  }
  float kv[4] = { (a0.x + a0.y) + (a0.z + a0.w), (a1.x + a1.y) + (a1.z + a1.w),
                  (a2.x + a2.y) + (a2.z + a2.w), (a3.x + a3.y) + (a3.z + a3.w) };
  float p = 0.f;
#pragma unroll
  for (int j = 0; j < 4; j++) {
    if (s == tq * 4 + j) kv[j] += 1e-6f;
    p += fabsf(kv[j]);
    Km[(size_t)b * 1024 + s * 32 + tq * 4 + j] = kv[j];
  }
  p += __shfl_xor(p, 1); p += __shfl_xor(p, 2); p += __shfl_xor(p, 4);
  __syncthreads();  // everyone done reading es; reuse as scratch
  float* rs = &es[0][0];
  if (tq == 0) rs[s] = p;
  __syncthreads();
  if (tid < 32) {
    float m = rs[tid];
    m = fmaxf(m, __shfl_xor(m, 1));
    m = fmaxf(m, __shfl_xor(m, 2));
    m = fmaxf(m, __shfl_xor(m, 4));
    m = fmaxf(m, __shfl_xor(m, 8));
    m = fmaxf(m, __shfl_xor(m, 16));
    if (tid == 0) eta2v[b] = 1.4426950408889634f / (2.0f * m);
  }
}

// ---------- QP: 500 exponentiated-gradient iterations, one wave per task ----------
__global__ __launch_bounds__(256) void qp_kernel(const float* __restrict__ Km,
                                                 const float* __restrict__ eta2v,
                                                 float* __restrict__ alp) {
  const int lane = threadIdx.x & 63, wid = threadIdx.x >> 6;
  const int b = blockIdx.x * 4 + wid;
  const int s = lane & 31;
  const float* Kb = Km + (size_t)b * 1024;
  float kr[32];
#pragma unroll
  for (int i = 0; i < 8; i++) {
    float4 v = ((const float4*)(Kb + s * 32))[i];
    kr[i * 4 + 0] = v.x; kr[i * 4 + 1] = v.y; kr[i * 4 + 2] = v.z; kr[i * 4 + 3] = v.w;
  }
  const float kd = Kb[s * 33];
  const float eta2 = eta2v[b];
  float a = 0.03125f;
  for (int it = 0; it < 500; ++it) {
    float c0 = 0.f, c1 = 0.f, c2 = 0.f, c3 = 0.f;
#pragma unroll
    for (int t = 0; t < 32; t += 4) {
      c0 = fmaf(kr[t + 0], lane_f(a, t + 0), c0);
      c1 = fmaf(kr[t + 1], lane_f(a, t + 1), c1);
      c2 = fmaf(kr[t + 2], lane_f(a, t + 2), c2);
      c3 = fmaf(kr[t + 3], lane_f(a, t + 3), c3);
    }
    float g = fmaf(2.f, (c0 + c1) + (c2 + c3), -kd);
    float z = __log2f(a + 1e-30f) - eta2 * g;       // base-2 logits (no max-sub: range safe)
    float e = __builtin_amdgcn_exp2f(z);
    float r = e;
    r += __int_as_float(__builtin_amdgcn_update_dpp(0, __float_as_int(r), 0x128, 0xf, 0xf, true)); // ror 8
    r += __int_as_float(__builtin_amdgcn_update_dpp(0, __float_as_int(r), 0x124, 0xf, 0xf, true)); // ror 4
    r += __int_as_float(__builtin_amdgcn_update_dpp(0, __float_as_int(r), 0x122, 0xf, 0xf, true)); // ror 2
    r += __int_as_float(__builtin_amdgcn_update_dpp(0, __float_as_int(r), 0x121, 0xf, 0xf, true)); // ror 1
    r += __shfl_xor(r, 16);                          // combine the two 16-groups
    a = e * __builtin_amdgcn_rcpf(r);
  }
  if (lane < 32) alp[(size_t)b * 32 + s] = a;
}

// ---------- centers[b] = sum_s alpha[b][s] * Es[b][s][:] ----------
__global__ __launch_bounds__(128) void centers_k(const float* __restrict__ alp,
                                                 const float* __restrict__ E,
                                                 float* __restrict__ ctr) {
  const int b = blockIdx.x, t = threadIdx.x;  // t 0..127 -> float4 col
  __shared__ float av[32];
  if (t < 32) av[t] = alp[(size_t)b * 32 + t];
  __syncthreads();
  const float4* Eb = (const float4*)(E + (size_t)b * 32 * 512);
  float4 c = {0, 0, 0, 0};
#pragma unroll 8
  for (int sIdx = 0; sIdx < 32; sIdx++) {
    float a = av[sIdx];
    float4 v = Eb[sIdx * 128 + t];
    c.x = fmaf(a, v.x, c.x); c.y = fmaf(a, v.y, c.y);
    c.z = fmaf(a, v.z, c.z); c.w = fmaf(a, v.w, c.w);
  }
  ((float4*)ctr)[b * 128 + t] = c;
}

// ---------- logits[b][q] = -||center[b] - Eq[b][q]||^2 ----------
__global__ __launch_bounds__(256) void logits_k(const float* __restrict__ ctr,
                                                const float* __restrict__ E,
                                                float* __restrict__ out) {
  const int b = blockIdx.x, lane = threadIdx.x & 63, w = threadIdx.x >> 6;
  const float4* C4 = (const float4*)(ctr + (size_t)b * 512);
  const float4 cA = C4[lane * 2], cB = C4[lane * 2 + 1];
  const float4* Q4 = (const float4*)(E + (size_t)(8192 + b * 64) * 512);
  for (int q = w; q < 64; q += 4) {
    float4 e0 = Q4[(size_t)q * 128 + lane * 2];
    float4 e1 = Q4[(size_t)q * 128 + lane * 2 + 1];
    float d, ss = 0.f;
    d = cA.x - e0.x; ss = fmaf(d, d, ss);
    d = cA.y - e0.y; ss = fmaf(d, d, ss);
    d = cA.z - e0.z; ss = fmaf(d, d, ss);
    d = cA.w - e0.w; ss = fmaf(d, d, ss);
    d = cB.x - e1.x; ss = fmaf(d, d, ss);
    d = cB.y - e1.y; ss = fmaf(d, d, ss);
    d = cB.z - e1.z; ss = fmaf(d, d, ss);
    d = cB.w - e1.w; ss = fmaf(d, d, ss);
    ss += __shfl_xor(ss, 1);  ss += __shfl_xor(ss, 2);  ss += __shfl_xor(ss, 4);
    ss += __shfl_xor(ss, 8);  ss += __shfl_xor(ss, 16); ss += __shfl_xor(ss, 32);
    if (lane == 0) out[b * 64 + q] = -ss;
  }
}

// ---------- launch ----------
extern "C" void kernel_launch(void* const* d_in, const int* in_sizes, int n_in,
                              void* d_out, int out_size, void* d_ws, size_t ws_size,
                              hipStream_t stream) {
  const float* sup = (const float*)d_in[0];
  const float* qry = (const float*)d_in[1];
  const float* W1  = (const float*)d_in[2];
  const float* b1  = (const float*)d_in[3];
  const float* W2  = (const float*)d_in[4];
  const float* b2  = (const float*)d_in[5];
  float* out = (float*)d_out;

  char* ws = (char*)d_ws;
  unsigned short* H   = (unsigned short*)(ws);               // 24576*2048*2 = 100,663,296
  unsigned short* Xbf = (unsigned short*)(ws + 100663296);   // 24576*1024*2 = 50,331,648
  float* E    = (float*)(ws + 100663296);                    // aliases Xbf (dead after GEMM1)
  unsigned short* W1T = (unsigned short*)(ws + 150994944);   // 4,194,304
  unsigned short* W2T = (unsigned short*)(ws + 155189248);   // 2,097,152
  float* Km   = (float*)(ws + 157286400);                    // 1,048,576
  float* eta2 = (float*)(ws + 158334976);                    // 1,024
  float* alp  = (float*)(ws + 158336000);                    // 32,768
  float* ctr  = (float*)(ws + 158368768);                    // 524,288
  // total ~158.9 MB

  castx<<<dim3(2048), dim3(256), 0, stream>>>(sup, qry, Xbf);
  transcast<<<dim3(64, 32), dim3(256), 0, stream>>>(W1, W1T, 1024, 2048);
  transcast<<<dim3(16, 64), dim3(256), 0, stream>>>(W2, W2T, 2048, 512);
  gemm_bt<1, 1><<<dim3(16, 192), dim3(256), 0, stream>>>(Xbf, W1T, b1, (void*)H, 24576, 2048, 1024);
  gemm_bt<0, 0><<<dim3(4, 192), dim3(256), 0, stream>>>(H, W2T, b2, (void*)E, 24576, 512, 2048);
  makeK<<<dim3(256), dim3(256), 0, stream>>>(E, Km, eta2);
  qp_kernel<<<dim3(64), dim3(256), 0, stream>>>(Km, eta2, alp);
  centers_k<<<dim3(256), dim3(128), 0, stream>>>(alp, E, ctr);
  logits_k<<<dim3(256), dim3(256), 0, stream>>>(ctr, E, out);
}

// Round 2
// 329.086 us; speedup vs baseline: 1.2023x; 1.2023x over previous
//
#include <hip/hip_runtime.h>
#include <hip/hip_bf16.h>

// ---------- helpers ----------
typedef __attribute__((ext_vector_type(8))) short bf16x8;
typedef __attribute__((ext_vector_type(4))) float f32x4;
typedef __attribute__((ext_vector_type(4))) unsigned short us4;

__device__ __forceinline__ unsigned short bf16_rne(float f) {
  unsigned u = __float_as_uint(f);
  unsigned r = u + 0x7fffu + ((u >> 16) & 1u);
  return (unsigned short)(r >> 16);
}

__device__ __forceinline__ void gload16(const void* g, void* l) {
  typedef const __attribute__((address_space(1))) unsigned int* gas;
  typedef __attribute__((address_space(3))) unsigned int* las;
  __builtin_amdgcn_global_load_lds((gas)g, (las)l, 16, 0, 0);
}

__device__ __forceinline__ float lane_f(float v, int l) {
  return __int_as_float(__builtin_amdgcn_readlane(__float_as_int(v), l));
}

#define BAR() asm volatile("s_barrier" ::: "memory")
#define VMCNT4() asm volatile("s_waitcnt vmcnt(4)" ::: "memory")

// ---------- cast inputs (support+query) f32 -> bf16, flat [24576][1024] ----------
__global__ __launch_bounds__(256) void castx(const float* __restrict__ sup,
                                             const float* __restrict__ qry,
                                             unsigned short* __restrict__ X) {
  const int stride = gridDim.x * blockDim.x;
  for (int i = blockIdx.x * blockDim.x + threadIdx.x; i < 6291456; i += stride) {
    float4 v = (i < 2097152) ? ((const float4*)sup)[i] : ((const float4*)qry)[i - 2097152];
    us4 o = { bf16_rne(v.x), bf16_rne(v.y), bf16_rne(v.z), bf16_rne(v.w) };
    *(us4*)(X + (size_t)i * 4) = o;
  }
}

// ---------- transpose+cast W [R][C] f32 -> WT [C][R] bf16 ----------
__global__ __launch_bounds__(256) void transcast(const float* __restrict__ src,
                                                 unsigned short* __restrict__ dst,
                                                 int R, int C) {
  __shared__ float t[32][33];
  const int tx = threadIdx.x & 31, ty = threadIdx.x >> 5;
  const int c0 = blockIdx.x * 32, r0 = blockIdx.y * 32;
#pragma unroll
  for (int j = 0; j < 4; j++)
    t[ty + j * 8][tx] = src[(size_t)(r0 + ty + j * 8) * C + c0 + tx];
  __syncthreads();
#pragma unroll
  for (int j = 0; j < 4; j++)
    dst[(size_t)(c0 + ty + j * 8) * R + r0 + tx] = bf16_rne(t[tx][ty + j * 8]);
}

// ---------- 256x256 8-phase bf16 GEMM: C = act(A[M][K] * BT[N][K]^T + bias) ----------
// 8 waves (2Mx4N), BK=64, 128KiB LDS double-buffer, counted vmcnt(4), read-side
// XOR swizzle (row bits 1,2 -> chunk bits 4,5) with matching pre-swizzled source.
#define MFMA_Q(AO, BO, MOFF, NOFF)                                                  \
  __builtin_amdgcn_s_setprio(1);                                                    \
  _Pragma("unroll") for (int i_ = 0; i_ < 4; ++i_)                                  \
  _Pragma("unroll") for (int j_ = 0; j_ < 2; ++j_)                                  \
  _Pragma("unroll") for (int ks_ = 0; ks_ < 2; ++ks_)                               \
    acc[(MOFF) + i_][(NOFF) + j_] = __builtin_amdgcn_mfma_f32_16x16x32_bf16(        \
        AO[i_][ks_], BO[j_][ks_], acc[(MOFF) + i_][(NOFF) + j_], 0, 0, 0);          \
  __builtin_amdgcn_s_setprio(0);

template <int ACT, int OUTBF>
__global__ __launch_bounds__(512, 2) void gemm256(const unsigned short* __restrict__ A,
                                                  const unsigned short* __restrict__ BT,
                                                  const float* __restrict__ bias,
                                                  void* __restrict__ Cout,
                                                  int M, int N, int K) {
  __shared__ __attribute__((aligned(16))) short ls[2][2][16384];  // [buf][A/B][256*64 bf16]
  const int tid = threadIdx.x, lane = tid & 63, wid = tid >> 6;
  const int wm = wid >> 2, wn = wid & 3;
  const int l15 = lane & 15, lg = lane >> 4;

  // bijective XCD swizzle (nwg % 8 == 0 for both GEMMs)
  int lin = blockIdx.y * gridDim.x + blockIdx.x;
  int nwg = gridDim.x * gridDim.y;
  int swz = (lin & 7) * (nwg >> 3) + (lin >> 3);
  int bx = swz % gridDim.x, by = swz / gridDim.x;
  const int m0 = by * 256, n0 = bx * 256;

  const size_t ld = (size_t)K * 2;
  const char* Ag = (const char*)A + (size_t)m0 * ld;
  const char* Bg = (const char*)BT + (size_t)n0 * ld;
  const int NT = K >> 6;

  auto STAGE = [&](char* lbase, int half, const char* g0, int tt) {
#pragma unroll
    for (int c = 0; c < 2; ++c) {
      int Pu = half * 16384 + c * 8192 + wid * 1024;     // wave-uniform LDS dest
      int P = Pu + lane * 16;                            // per-lane dest byte
      int row = P >> 7;
      int kb = (P & 127) ^ (((P >> 9) & 1) << 5) ^ (((P >> 8) & 1) << 4);
      gload16(g0 + (size_t)row * ld + (size_t)tt * 128 + kb, lbase + Pu);
    }
  };
  auto RD = [&](const char* lb, int r0, int ks) -> bf16x8 {
    int L = (r0 + l15) * 128 + ks * 64 + lg * 16;
    L ^= (((L >> 9) & 1) << 5) ^ (((L >> 8) & 1) << 4);
    return *(const bf16x8*)(lb + L);
  };

  f32x4 acc[8][4] = {};
  bf16x8 afr[4][2], bfr0[2][2], bfr1[2][2];

  // prologue: tile0 fully + B-halves of tile1; then wait through tile0, barrier
  STAGE((char*)ls[0][0], 0, Ag, 0);
  STAGE((char*)ls[0][0], 1, Ag, 0);
  STAGE((char*)ls[0][1], 0, Bg, 0);
  STAGE((char*)ls[0][1], 1, Bg, 0);
  STAGE((char*)ls[1][1], 0, Bg, 1);
  STAGE((char*)ls[1][1], 1, Bg, 1);
  VMCNT4();
  BAR();

  for (int u = 0; u < NT; ++u) {
    const int bs = u & 1;
    const char* lab = (const char*)ls[bs][0];
    const char* lbb = (const char*)ls[bs][1];
    char* lan = (char*)ls[bs ^ 1][0];
    char* lbn = (char*)ls[bs][1];
    int t1 = u + 1; if (t1 == NT) t1 = 0;        // wrap keeps vmcnt accounting uniform
    int t2 = u + 2; if (t2 >= NT) t2 -= NT;

    // q0: read A(mh0)+B(nh0), stage A0(u+1)
#pragma unroll
    for (int i = 0; i < 4; ++i)
#pragma unroll
      for (int ks = 0; ks < 2; ++ks) afr[i][ks] = RD(lab, wm * 128 + i * 16, ks);
#pragma unroll
    for (int j = 0; j < 2; ++j)
#pragma unroll
      for (int ks = 0; ks < 2; ++ks) bfr0[j][ks] = RD(lbb, wn * 64 + j * 16, ks);
    STAGE(lan, 0, Ag, t1);
    BAR();
    MFMA_Q(afr, bfr0, 0, 0);
    BAR();
    // q1: read B(nh1), stage A1(u+1)
#pragma unroll
    for (int j = 0; j < 2; ++j)
#pragma unroll
      for (int ks = 0; ks < 2; ++ks) bfr1[j][ks] = RD(lbb, wn * 64 + 32 + j * 16, ks);
    STAGE(lan, 1, Ag, t1);
    BAR();
    MFMA_Q(afr, bfr1, 0, 2);
    BAR();
    // q2: read A(mh1), stage B0(u+2) (B of this buffer fully read in q0/q1)
#pragma unroll
    for (int i = 0; i < 4; ++i)
#pragma unroll
      for (int ks = 0; ks < 2; ++ks) afr[i][ks] = RD(lab, wm * 128 + 64 + i * 16, ks);
    STAGE(lbn, 0, Bg, t2);
    BAR();
    MFMA_Q(afr, bfr1, 4, 2);
    BAR();
    // q3: stage B1(u+2), counted vmcnt: everything through A1(u+1) landed
    STAGE(lbn, 1, Bg, t2);
    VMCNT4();
    BAR();
    MFMA_Q(afr, bfr0, 4, 0);
    BAR();
  }

  float bv[4];
#pragma unroll
  for (int nf = 0; nf < 4; ++nf) bv[nf] = bias[n0 + wn * 64 + nf * 16 + l15];
#pragma unroll
  for (int mf = 0; mf < 8; ++mf) {
    int rbase = m0 + wm * 128 + mf * 16 + lg * 4;
#pragma unroll
    for (int nf = 0; nf < 4; ++nf) {
      int col = n0 + wn * 64 + nf * 16 + l15;
#pragma unroll
      for (int j = 0; j < 4; ++j) {
        float v = acc[mf][nf][j] + bv[nf];
        if (ACT) v = v > 0.f ? v : 0.f;
        size_t idx = (size_t)(rbase + j) * N + col;
        if (OUTBF) ((unsigned short*)Cout)[idx] = bf16_rne(v);
        else       ((float*)Cout)[idx] = v;
      }
    }
  }
}

// ---------- per-task K = Es Es^T + eps*I, eta2 = log2(e)/(2*max row abs-sum) ----------
__global__ __launch_bounds__(256) void makeK(const float* __restrict__ E,
                                             float* __restrict__ Km,
                                             float* __restrict__ eta2v) {
  __shared__ float es[32][512];  // 64 KB
  const int b = blockIdx.x, tid = threadIdx.x;
  const float4* Eb = (const float4*)(E + (size_t)b * 32 * 512);
  float4* es4 = (float4*)&es[0][0];
  for (int i = tid; i < 32 * 128; i += 256) es4[i] = Eb[i];
  __syncthreads();

  const int s = tid >> 3, tq = tid & 7;
  const float4* rs4 = (const float4*)&es[s][0];
  const float4* rt0 = (const float4*)&es[tq * 4 + 0][0];
  const float4* rt1 = (const float4*)&es[tq * 4 + 1][0];
  const float4* rt2 = (const float4*)&es[tq * 4 + 2][0];
  const float4* rt3 = (const float4*)&es[tq * 4 + 3][0];
  float4 a0 = {0, 0, 0, 0}, a1 = {0, 0, 0, 0}, a2 = {0, 0, 0, 0}, a3 = {0, 0, 0, 0};
  for (int dd = 0; dd < 128; ++dd) {
    float4 av = rs4[dd];
    float4 b0 = rt0[dd], b1 = rt1[dd], b2 = rt2[dd], b3 = rt3[dd];
    a0.x = fmaf(av.x, b0.x, a0.x); a0.y = fmaf(av.y, b0.y, a0.y);
    a0.z = fmaf(av.z, b0.z, a0.z); a0.w = fmaf(av.w, b0.w, a0.w);
    a1.x = fmaf(av.x, b1.x, a1.x); a1.y = fmaf(av.y, b1.y, a1.y);
    a1.z = fmaf(av.z, b1.z, a1.z); a1.w = fmaf(av.w, b1.w, a1.w);
    a2.x = fmaf(av.x, b2.x, a2.x); a2.y = fmaf(av.y, b2.y, a2.y);
    a2.z = fmaf(av.z, b2.z, a2.z); a2.w = fmaf(av.w, b2.w, a2.w);
    a3.x = fmaf(av.x, b3.x, a3.x); a3.y = fmaf(av.y, b3.y, a3.y);
    a3.z = fmaf(av.z, b3.z, a3.z); a3.w = fmaf(av.w, b3.w, a3.w);
  }
  float kv[4] = { (a0.x + a0.y) + (a0.z + a0.w), (a1.x + a1.y) + (a1.z + a1.w),
                  (a2.x + a2.y) + (a2.z + a2.w), (a3.x + a3.y) + (a3.z + a3.w) };
  float p = 0.f;
#pragma unroll
  for (int j = 0; j < 4; j++) {
    if (s == tq * 4 + j) kv[j] += 1e-6f;
    p += fabsf(kv[j]);
    Km[(size_t)b * 1024 + s * 32 + tq * 4 + j] = kv[j];
  }
  p += __shfl_xor(p, 1); p += __shfl_xor(p, 2); p += __shfl_xor(p, 4);
  __syncthreads();
  float* rs = &es[0][0];
  if (tq == 0) rs[s] = p;
  __syncthreads();
  if (tid < 32) {
    float m = rs[tid];
    m = fmaxf(m, __shfl_xor(m, 1));
    m = fmaxf(m, __shfl_xor(m, 2));
    m = fmaxf(m, __shfl_xor(m, 4));
    m = fmaxf(m, __shfl_xor(m, 8));
    m = fmaxf(m, __shfl_xor(m, 16));
    if (tid == 0) eta2v[b] = 1.4426950408889634f / (2.0f * m);
  }
}

// ---------- QP: 500 EG iterations in unnormalized w-space, one wave per task ----------
// w' = (w*rcp(S)) * 2^z,  z = fma(-2*eta2*rcp(S), (K w), eta2*kd)  [== softmax recursion]
__global__ __launch_bounds__(256) void qp_kernel(const float* __restrict__ Km,
                                                 const float* __restrict__ eta2v,
                                                 float* __restrict__ alp) {
  const int lane = threadIdx.x & 63, wid = threadIdx.x >> 6;
  const int b = blockIdx.x * 4 + wid;
  const int s = lane & 31;
  const float* Kb = Km + (size_t)b * 1024;
  float kr[32];
#pragma unroll
  for (int i = 0; i < 8; i++) {
    float4 v = ((const float4*)(Kb + s * 32))[i];
    kr[i * 4 + 0] = v.x; kr[i * 4 + 1] = v.y; kr[i * 4 + 2] = v.z; kr[i * 4 + 3] = v.w;
  }
  const float kd = Kb[s * 33];
  const float eta2 = eta2v[b];
  const float c2 = eta2 * kd;
  const float m2n = -2.0f * eta2;
  float w = 0.03125f;
  for (int it = 0; it < 500; ++it) {
    float c0 = 0.f, c1 = 0.f, ca = 0.f, c3 = 0.f;
#pragma unroll
    for (int t = 0; t < 32; t += 4) {
      c0 = fmaf(kr[t + 0], lane_f(w, t + 0), c0);
      c1 = fmaf(kr[t + 1], lane_f(w, t + 1), c1);
      ca = fmaf(kr[t + 2], lane_f(w, t + 2), ca);
      c3 = fmaf(kr[t + 3], lane_f(w, t + 3), c3);
    }
    float tK = (c0 + c1) + (ca + c3);
    // S reduction (independent of matvec -> overlaps)
    float r = w;
    r += __int_as_float(__builtin_amdgcn_update_dpp(0, __float_as_int(r), 0x128, 0xf, 0xf, true));
    r += __int_as_float(__builtin_amdgcn_update_dpp(0, __float_as_int(r), 0x124, 0xf, 0xf, true));
    r += __int_as_float(__builtin_amdgcn_update_dpp(0, __float_as_int(r), 0x122, 0xf, 0xf, true));
    r += __int_as_float(__builtin_amdgcn_update_dpp(0, __float_as_int(r), 0x121, 0xf, 0xf, true));
    r += __shfl_xor(r, 16);
    float R = __builtin_amdgcn_rcpf(r);
    float z = fmaf(m2n * R, tK, c2);
    w = w * R * __builtin_amdgcn_exp2f(z);
  }
  // final normalize
  float r = w;
  r += __int_as_float(__builtin_amdgcn_update_dpp(0, __float_as_int(r), 0x128, 0xf, 0xf, true));
  r += __int_as_float(__builtin_amdgcn_update_dpp(0, __float_as_int(r), 0x124, 0xf, 0xf, true));
  r += __int_as_float(__builtin_amdgcn_update_dpp(0, __float_as_int(r), 0x122, 0xf, 0xf, true));
  r += __int_as_float(__builtin_amdgcn_update_dpp(0, __float_as_int(r), 0x121, 0xf, 0xf, true));
  r += __shfl_xor(r, 16);
  float R = __builtin_amdgcn_rcpf(r);
  if (lane < 32) alp[(size_t)b * 32 + s] = w * R;
}

// ---------- centers[b] = sum_s alpha[b][s] * Es[b][s][:] ----------
__global__ __launch_bounds__(128) void centers_k(const float* __restrict__ alp,
                                                 const float* __restrict__ E,
                                                 float* __restrict__ ctr) {
  const int b = blockIdx.x, t = threadIdx.x;
  __shared__ float av[32];
  if (t < 32) av[t] = alp[(size_t)b * 32 + t];
  __syncthreads();
  const float4* Eb = (const float4*)(E + (size_t)b * 32 * 512);
  float4 c = {0, 0, 0, 0};
#pragma unroll 8
  for (int sIdx = 0; sIdx < 32; sIdx++) {
    float a = av[sIdx];
    float4 v = Eb[sIdx * 128 + t];
    c.x = fmaf(a, v.x, c.x); c.y = fmaf(a, v.y, c.y);
    c.z = fmaf(a, v.z, c.z); c.w = fmaf(a, v.w, c.w);
  }
  ((float4*)ctr)[b * 128 + t] = c;
}

// ---------- logits[b][q] = -||center[b] - Eq[b][q]||^2 ----------
__global__ __launch_bounds__(256) void logits_k(const float* __restrict__ ctr,
                                                const float* __restrict__ E,
                                                float* __restrict__ out) {
  const int b = blockIdx.x, lane = threadIdx.x & 63, w = threadIdx.x >> 6;
  const float4* C4 = (const float4*)(ctr + (size_t)b * 512);
  const float4 cA = C4[lane * 2], cB = C4[lane * 2 + 1];
  const float4* Q4 = (const float4*)(E + (size_t)(8192 + b * 64) * 512);
  for (int q = w; q < 64; q += 4) {
    float4 e0 = Q4[(size_t)q * 128 + lane * 2];
    float4 e1 = Q4[(size_t)q * 128 + lane * 2 + 1];
    float d, ss = 0.f;
    d = cA.x - e0.x; ss = fmaf(d, d, ss);
    d = cA.y - e0.y; ss = fmaf(d, d, ss);
    d = cA.z - e0.z; ss = fmaf(d, d, ss);
    d = cA.w - e0.w; ss = fmaf(d, d, ss);
    d = cB.x - e1.x; ss = fmaf(d, d, ss);
    d = cB.y - e1.y; ss = fmaf(d, d, ss);
    d = cB.z - e1.z; ss = fmaf(d, d, ss);
    d = cB.w - e1.w; ss = fmaf(d, d, ss);
    ss += __shfl_xor(ss, 1);  ss += __shfl_xor(ss, 2);  ss += __shfl_xor(ss, 4);
    ss += __shfl_xor(ss, 8);  ss += __shfl_xor(ss, 16); ss += __shfl_xor(ss, 32);
    if (lane == 0) out[b * 64 + q] = -ss;
  }
}

// ---------- launch ----------
extern "C" void kernel_launch(void* const* d_in, const int* in_sizes, int n_in,
                              void* d_out, int out_size, void* d_ws, size_t ws_size,
                              hipStream_t stream) {
  const float* sup = (const float*)d_in[0];
  const float* qry = (const float*)d_in[1];
  const float* W1  = (const float*)d_in[2];
  const float* b1  = (const float*)d_in[3];
  const float* W2  = (const float*)d_in[4];
  const float* b2  = (const float*)d_in[5];
  float* out = (float*)d_out;

  char* ws = (char*)d_ws;
  unsigned short* H   = (unsigned short*)(ws);               // 24576*2048*2
  unsigned short* Xbf = (unsigned short*)(ws + 100663296);   // 24576*1024*2
  float* E    = (float*)(ws + 100663296);                    // aliases Xbf (dead after GEMM1)
  unsigned short* W1T = (unsigned short*)(ws + 150994944);
  unsigned short* W2T = (unsigned short*)(ws + 155189248);
  float* Km   = (float*)(ws + 157286400);
  float* eta2 = (float*)(ws + 158334976);
  float* alp  = (float*)(ws + 158336000);
  float* ctr  = (float*)(ws + 158368768);

  castx<<<dim3(2048), dim3(256), 0, stream>>>(sup, qry, Xbf);
  transcast<<<dim3(64, 32), dim3(256), 0, stream>>>(W1, W1T, 1024, 2048);
  transcast<<<dim3(16, 64), dim3(256), 0, stream>>>(W2, W2T, 2048, 512);
  gemm256<1, 1><<<dim3(8, 96), dim3(512), 0, stream>>>(Xbf, W1T, b1, (void*)H, 24576, 2048, 1024);
  gemm256<0, 0><<<dim3(2, 96), dim3(512), 0, stream>>>(H, W2T, b2, (void*)E, 24576, 512, 2048);
  makeK<<<dim3(256), dim3(256), 0, stream>>>(E, Km, eta2);
  qp_kernel<<<dim3(64), dim3(256), 0, stream>>>(Km, eta2, alp);
  centers_k<<<dim3(256), dim3(128), 0, stream>>>(alp, E, ctr);
  logits_k<<<dim3(256), dim3(256), 0, stream>>>(ctr, E, out);
}

// Round 3
// 315.772 us; speedup vs baseline: 1.2530x; 1.0422x over previous
//
#include <hip/hip_runtime.h>
#include <hip/hip_bf16.h>

// ---------- helpers ----------
typedef __attribute__((ext_vector_type(8))) short bf16x8;
typedef __attribute__((ext_vector_type(4))) float f32x4;
typedef __attribute__((ext_vector_type(4))) unsigned short us4;

__device__ __forceinline__ unsigned short bf16_rne(float f) {
  unsigned u = __float_as_uint(f);
  unsigned r = u + 0x7fffu + ((u >> 16) & 1u);
  return (unsigned short)(r >> 16);
}

__device__ __forceinline__ void gload16(const void* g, void* l) {
  typedef const __attribute__((address_space(1))) unsigned int* gas;
  typedef __attribute__((address_space(3))) unsigned int* las;
  __builtin_amdgcn_global_load_lds((gas)g, (las)l, 16, 0, 0);
}

__device__ __forceinline__ float lane_f(float v, int l) {
  return __int_as_float(__builtin_amdgcn_readlane(__float_as_int(v), l));
}

#define BAR() asm volatile("s_barrier" ::: "memory")
#define VMCNT4() asm volatile("s_waitcnt vmcnt(4)" ::: "memory")

// ---------- cast inputs (support+query) f32 -> bf16, flat [24576][1024] ----------
__global__ __launch_bounds__(256) void castx(const float* __restrict__ sup,
                                             const float* __restrict__ qry,
                                             unsigned short* __restrict__ X) {
  const int stride = gridDim.x * blockDim.x;
  for (int i = blockIdx.x * blockDim.x + threadIdx.x; i < 6291456; i += stride) {
    float4 v = (i < 2097152) ? ((const float4*)sup)[i] : ((const float4*)qry)[i - 2097152];
    us4 o = { bf16_rne(v.x), bf16_rne(v.y), bf16_rne(v.z), bf16_rne(v.w) };
    *(us4*)(X + (size_t)i * 4) = o;
  }
}

// ---------- transpose+cast W [R][C] f32 -> WT [C][R] bf16 ----------
__global__ __launch_bounds__(256) void transcast(const float* __restrict__ src,
                                                 unsigned short* __restrict__ dst,
                                                 int R, int C) {
  __shared__ float t[32][33];
  const int tx = threadIdx.x & 31, ty = threadIdx.x >> 5;
  const int c0 = blockIdx.x * 32, r0 = blockIdx.y * 32;
#pragma unroll
  for (int j = 0; j < 4; j++)
    t[ty + j * 8][tx] = src[(size_t)(r0 + ty + j * 8) * C + c0 + tx];
  __syncthreads();
#pragma unroll
  for (int j = 0; j < 4; j++)
    dst[(size_t)(c0 + ty + j * 8) * R + r0 + tx] = bf16_rne(t[tx][ty + j * 8]);
}

// ---------- 256x256 8-phase bf16 GEMM: C = act(A[M][K] * BT[N][K]^T + bias) ----------
// 8 waves (2Mx4N), BK=64, 128KiB LDS double-buffer, counted vmcnt(4).
// FULL 3-bit XOR swizzle (byte ^= (row&7)<<4, G4 prescription): rows 0..7 spread
// across all 8 16B slots -> ds_read_b128 hits the 8-lanes/slot LDS floor.
// Same involution pre-applied to the global_load_lds SOURCE column (rule #21).
#define MFMA_Q(AO, BO, MOFF, NOFF)                                                  \
  __builtin_amdgcn_s_setprio(1);                                                    \
  _Pragma("unroll") for (int i_ = 0; i_ < 4; ++i_)                                  \
  _Pragma("unroll") for (int j_ = 0; j_ < 2; ++j_)                                  \
  _Pragma("unroll") for (int ks_ = 0; ks_ < 2; ++ks_)                               \
    acc[(MOFF) + i_][(NOFF) + j_] = __builtin_amdgcn_mfma_f32_16x16x32_bf16(        \
        AO[i_][ks_], BO[j_][ks_], acc[(MOFF) + i_][(NOFF) + j_], 0, 0, 0);          \
  __builtin_amdgcn_s_setprio(0);

template <int ACT, int OUTBF>
__global__ __launch_bounds__(512, 2) void gemm256(const unsigned short* __restrict__ A,
                                                  const unsigned short* __restrict__ BT,
                                                  const float* __restrict__ bias,
                                                  void* __restrict__ Cout,
                                                  int M, int N, int K) {
  __shared__ __attribute__((aligned(16))) short ls[2][2][16384];  // [buf][A/B][256*64 bf16]
  const int tid = threadIdx.x, lane = tid & 63, wid = tid >> 6;
  const int wm = wid >> 2, wn = wid & 3;
  const int l15 = lane & 15, lg = lane >> 4;

  // bijective XCD swizzle (nwg % 8 == 0 for both GEMMs)
  int lin = blockIdx.y * gridDim.x + blockIdx.x;
  int nwg = gridDim.x * gridDim.y;
  int swz = (lin & 7) * (nwg >> 3) + (lin >> 3);
  int bx = swz % gridDim.x, by = swz / gridDim.x;
  const int m0 = by * 256, n0 = bx * 256;

  const size_t ld = (size_t)K * 2;
  const char* Ag = (const char*)A + (size_t)m0 * ld;
  const char* Bg = (const char*)BT + (size_t)n0 * ld;
  const int NT = K >> 6;

  auto STAGE = [&](char* lbase, int half, const char* g0, int tt) {
#pragma unroll
    for (int c = 0; c < 2; ++c) {
      int Pu = half * 16384 + c * 8192 + wid * 1024;     // wave-uniform LDS dest
      int P = Pu + lane * 16;                            // per-lane dest byte
      int row = P >> 7;
      int kb = (P & 127) ^ (((P >> 7) & 7) << 4);        // pre-swizzled source column
      gload16(g0 + (size_t)row * ld + (size_t)tt * 128 + kb, lbase + Pu);
    }
  };
  auto RD = [&](const char* lb, int r0, int ks) -> bf16x8 {
    int L = (r0 + l15) * 128 + ks * 64 + lg * 16;
    L ^= ((L >> 7) & 7) << 4;                            // same involution on read
    return *(const bf16x8*)(lb + L);
  };

  f32x4 acc[8][4] = {};
  bf16x8 afr[4][2], bfr0[2][2], bfr1[2][2];

  // prologue: tile0 fully + B-halves of tile1; then wait through tile0, barrier
  STAGE((char*)ls[0][0], 0, Ag, 0);
  STAGE((char*)ls[0][0], 1, Ag, 0);
  STAGE((char*)ls[0][1], 0, Bg, 0);
  STAGE((char*)ls[0][1], 1, Bg, 0);
  STAGE((char*)ls[1][1], 0, Bg, 1);
  STAGE((char*)ls[1][1], 1, Bg, 1);
  VMCNT4();
  BAR();

  for (int u = 0; u < NT; ++u) {
    const int bs = u & 1;
    const char* lab = (const char*)ls[bs][0];
    const char* lbb = (const char*)ls[bs][1];
    char* lan = (char*)ls[bs ^ 1][0];
    char* lbn = (char*)ls[bs][1];
    int t1 = u + 1; if (t1 == NT) t1 = 0;        // wrap keeps vmcnt accounting uniform
    int t2 = u + 2; if (t2 >= NT) t2 -= NT;

    // q0: read A(mh0)+B(nh0), stage A0(u+1)
#pragma unroll
    for (int i = 0; i < 4; ++i)
#pragma unroll
      for (int ks = 0; ks < 2; ++ks) afr[i][ks] = RD(lab, wm * 128 + i * 16, ks);
#pragma unroll
    for (int j = 0; j < 2; ++j)
#pragma unroll
      for (int ks = 0; ks < 2; ++ks) bfr0[j][ks] = RD(lbb, wn * 64 + j * 16, ks);
    STAGE(lan, 0, Ag, t1);
    BAR();
    MFMA_Q(afr, bfr0, 0, 0);
    BAR();
    // q1: read B(nh1), stage A1(u+1)
#pragma unroll
    for (int j = 0; j < 2; ++j)
#pragma unroll
      for (int ks = 0; ks < 2; ++ks) bfr1[j][ks] = RD(lbb, wn * 64 + 32 + j * 16, ks);
    STAGE(lan, 1, Ag, t1);
    BAR();
    MFMA_Q(afr, bfr1, 0, 2);
    BAR();
    // q2: read A(mh1), stage B0(u+2) (B of this buffer fully read in q0/q1)
#pragma unroll
    for (int i = 0; i < 4; ++i)
#pragma unroll
      for (int ks = 0; ks < 2; ++ks) afr[i][ks] = RD(lab, wm * 128 + 64 + i * 16, ks);
    STAGE(lbn, 0, Bg, t2);
    BAR();
    MFMA_Q(afr, bfr1, 4, 2);
    BAR();
    // q3: stage B1(u+2), counted vmcnt: everything through A1(u+1) landed
    STAGE(lbn, 1, Bg, t2);
    VMCNT4();
    BAR();
    MFMA_Q(afr, bfr0, 4, 0);
    BAR();
  }

  float bv[4];
#pragma unroll
  for (int nf = 0; nf < 4; ++nf) bv[nf] = bias[n0 + wn * 64 + nf * 16 + l15];
#pragma unroll
  for (int mf = 0; mf < 8; ++mf) {
    int rbase = m0 + wm * 128 + mf * 16 + lg * 4;
#pragma unroll
    for (int nf = 0; nf < 4; ++nf) {
      int col = n0 + wn * 64 + nf * 16 + l15;
#pragma unroll
      for (int j = 0; j < 4; ++j) {
        float v = acc[mf][nf][j] + bv[nf];
        if (ACT) v = v > 0.f ? v : 0.f;
        size_t idx = (size_t)(rbase + j) * N + col;
        if (OUTBF) ((unsigned short*)Cout)[idx] = bf16_rne(v);
        else       ((float*)Cout)[idx] = v;
      }
    }
  }
}

// ---------- per-task K = Es Es^T + eps*I, eta2 = log2(e)/(2*max row abs-sum) ----------
__global__ __launch_bounds__(256) void makeK(const float* __restrict__ E,
                                             float* __restrict__ Km,
                                             float* __restrict__ eta2v) {
  __shared__ float es[32][512];  // 64 KB
  const int b = blockIdx.x, tid = threadIdx.x;
  const float4* Eb = (const float4*)(E + (size_t)b * 32 * 512);
  float4* es4 = (float4*)&es[0][0];
  for (int i = tid; i < 32 * 128; i += 256) es4[i] = Eb[i];
  __syncthreads();

  const int s = tid >> 3, tq = tid & 7;
  const float4* rs4 = (const float4*)&es[s][0];
  const float4* rt0 = (const float4*)&es[tq * 4 + 0][0];
  const float4* rt1 = (const float4*)&es[tq * 4 + 1][0];
  const float4* rt2 = (const float4*)&es[tq * 4 + 2][0];
  const float4* rt3 = (const float4*)&es[tq * 4 + 3][0];
  float4 a0 = {0, 0, 0, 0}, a1 = {0, 0, 0, 0}, a2 = {0, 0, 0, 0}, a3 = {0, 0, 0, 0};
  for (int dd = 0; dd < 128; ++dd) {
    float4 av = rs4[dd];
    float4 b0 = rt0[dd], b1 = rt1[dd], b2 = rt2[dd], b3 = rt3[dd];
    a0.x = fmaf(av.x, b0.x, a0.x); a0.y = fmaf(av.y, b0.y, a0.y);
    a0.z = fmaf(av.z, b0.z, a0.z); a0.w = fmaf(av.w, b0.w, a0.w);
    a1.x = fmaf(av.x, b1.x, a1.x); a1.y = fmaf(av.y, b1.y, a1.y);
    a1.z = fmaf(av.z, b1.z, a1.z); a1.w = fmaf(av.w, b1.w, a1.w);
    a2.x = fmaf(av.x, b2.x, a2.x); a2.y = fmaf(av.y, b2.y, a2.y);
    a2.z = fmaf(av.z, b2.z, a2.z); a2.w = fmaf(av.w, b2.w, a2.w);
    a3.x = fmaf(av.x, b3.x, a3.x); a3.y = fmaf(av.y, b3.y, a3.y);
    a3.z = fmaf(av.z, b3.z, a3.z); a3.w = fmaf(av.w, b3.w, a3.w);
  }
  float kv[4] = { (a0.x + a0.y) + (a0.z + a0.w), (a1.x + a1.y) + (a1.z + a1.w),
                  (a2.x + a2.y) + (a2.z + a2.w), (a3.x + a3.y) + (a3.z + a3.w) };
  float p = 0.f;
#pragma unroll
  for (int j = 0; j < 4; j++) {
    if (s == tq * 4 + j) kv[j] += 1e-6f;
    p += fabsf(kv[j]);
    Km[(size_t)b * 1024 + s * 32 + tq * 4 + j] = kv[j];
  }
  p += __shfl_xor(p, 1); p += __shfl_xor(p, 2); p += __shfl_xor(p, 4);
  __syncthreads();
  float* rs = &es[0][0];
  if (tq == 0) rs[s] = p;
  __syncthreads();
  if (tid < 32) {
    float m = rs[tid];
    m = fmaxf(m, __shfl_xor(m, 1));
    m = fmaxf(m, __shfl_xor(m, 2));
    m = fmaxf(m, __shfl_xor(m, 4));
    m = fmaxf(m, __shfl_xor(m, 8));
    m = fmaxf(m, __shfl_xor(m, 16));
    if (tid == 0) eta2v[b] = 1.4426950408889634f / (2.0f * m);
  }
}

// ---------- QP: 500 EG iterations in unnormalized w-space, one wave per task ----------
// w' = (w*rcp(S)) * 2^z,  z = fma(-2*eta2*rcp(S), (K w), eta2*kd)  [== softmax recursion]
__global__ __launch_bounds__(256) void qp_kernel(const float* __restrict__ Km,
                                                 const float* __restrict__ eta2v,
                                                 float* __restrict__ alp) {
  const int lane = threadIdx.x & 63, wid = threadIdx.x >> 6;
  const int b = blockIdx.x * 4 + wid;
  const int s = lane & 31;
  const float* Kb = Km + (size_t)b * 1024;
  float kr[32];
#pragma unroll
  for (int i = 0; i < 8; i++) {
    float4 v = ((const float4*)(Kb + s * 32))[i];
    kr[i * 4 + 0] = v.x; kr[i * 4 + 1] = v.y; kr[i * 4 + 2] = v.z; kr[i * 4 + 3] = v.w;
  }
  const float kd = Kb[s * 33];
  const float eta2 = eta2v[b];
  const float c2 = eta2 * kd;
  const float m2n = -2.0f * eta2;
  float w = 0.03125f;
  for (int it = 0; it < 500; ++it) {
    float c0 = 0.f, c1 = 0.f, ca = 0.f, c3 = 0.f;
#pragma unroll
    for (int t = 0; t < 32; t += 4) {
      c0 = fmaf(kr[t + 0], lane_f(w, t + 0), c0);
      c1 = fmaf(kr[t + 1], lane_f(w, t + 1), c1);
      ca = fmaf(kr[t + 2], lane_f(w, t + 2), ca);
      c3 = fmaf(kr[t + 3], lane_f(w, t + 3), c3);
    }
    float tK = (c0 + c1) + (ca + c3);
    // S reduction (independent of matvec -> overlaps)
    float r = w;
    r += __int_as_float(__builtin_amdgcn_update_dpp(0, __float_as_int(r), 0x128, 0xf, 0xf, true));
    r += __int_as_float(__builtin_amdgcn_update_dpp(0, __float_as_int(r), 0x124, 0xf, 0xf, true));
    r += __int_as_float(__builtin_amdgcn_update_dpp(0, __float_as_int(r), 0x122, 0xf, 0xf, true));
    r += __int_as_float(__builtin_amdgcn_update_dpp(0, __float_as_int(r), 0x121, 0xf, 0xf, true));
    r += __shfl_xor(r, 16);
    float R = __builtin_amdgcn_rcpf(r);
    float z = fmaf(m2n * R, tK, c2);
    w = w * R * __builtin_amdgcn_exp2f(z);
  }
  // final normalize
  float r = w;
  r += __int_as_float(__builtin_amdgcn_update_dpp(0, __float_as_int(r), 0x128, 0xf, 0xf, true));
  r += __int_as_float(__builtin_amdgcn_update_dpp(0, __float_as_int(r), 0x124, 0xf, 0xf, true));
  r += __int_as_float(__builtin_amdgcn_update_dpp(0, __float_as_int(r), 0x122, 0xf, 0xf, true));
  r += __int_as_float(__builtin_amdgcn_update_dpp(0, __float_as_int(r), 0x121, 0xf, 0xf, true));
  r += __shfl_xor(r, 16);
  float R = __builtin_amdgcn_rcpf(r);
  if (lane < 32) alp[(size_t)b * 32 + s] = w * R;
}

// ---------- centers[b] = sum_s alpha[b][s] * Es[b][s][:] ----------
__global__ __launch_bounds__(128) void centers_k(const float* __restrict__ alp,
                                                 const float* __restrict__ E,
                                                 float* __restrict__ ctr) {
  const int b = blockIdx.x, t = threadIdx.x;
  __shared__ float av[32];
  if (t < 32) av[t] = alp[(size_t)b * 32 + t];
  __syncthreads();
  const float4* Eb = (const float4*)(E + (size_t)b * 32 * 512);
  float4 c = {0, 0, 0, 0};
#pragma unroll 8
  for (int sIdx = 0; sIdx < 32; sIdx++) {
    float a = av[sIdx];
    float4 v = Eb[sIdx * 128 + t];
    c.x = fmaf(a, v.x, c.x); c.y = fmaf(a, v.y, c.y);
    c.z = fmaf(a, v.z, c.z); c.w = fmaf(a, v.w, c.w);
  }
  ((float4*)ctr)[b * 128 + t] = c;
}

// ---------- logits[b][q] = -||center[b] - Eq[b][q]||^2 ----------
__global__ __launch_bounds__(256) void logits_k(const float* __restrict__ ctr,
                                                const float* __restrict__ E,
                                                float* __restrict__ out) {
  const int b = blockIdx.x, lane = threadIdx.x & 63, w = threadIdx.x >> 6;
  const float4* C4 = (const float4*)(ctr + (size_t)b * 512);
  const float4 cA = C4[lane * 2], cB = C4[lane * 2 + 1];
  const float4* Q4 = (const float4*)(E + (size_t)(8192 + b * 64) * 512);
  for (int q = w; q < 64; q += 4) {
    float4 e0 = Q4[(size_t)q * 128 + lane * 2];
    float4 e1 = Q4[(size_t)q * 128 + lane * 2 + 1];
    float d, ss = 0.f;
    d = cA.x - e0.x; ss = fmaf(d, d, ss);
    d = cA.y - e0.y; ss = fmaf(d, d, ss);
    d = cA.z - e0.z; ss = fmaf(d, d, ss);
    d = cA.w - e0.w; ss = fmaf(d, d, ss);
    d = cB.x - e1.x; ss = fmaf(d, d, ss);
    d = cB.y - e1.y; ss = fmaf(d, d, ss);
    d = cB.z - e1.z; ss = fmaf(d, d, ss);
    d = cB.w - e1.w; ss = fmaf(d, d, ss);
    ss += __shfl_xor(ss, 1);  ss += __shfl_xor(ss, 2);  ss += __shfl_xor(ss, 4);
    ss += __shfl_xor(ss, 8);  ss += __shfl_xor(ss, 16); ss += __shfl_xor(ss, 32);
    if (lane == 0) out[b * 64 + q] = -ss;
  }
}

// ---------- launch ----------
extern "C" void kernel_launch(void* const* d_in, const int* in_sizes, int n_in,
                              void* d_out, int out_size, void* d_ws, size_t ws_size,
                              hipStream_t stream) {
  const float* sup = (const float*)d_in[0];
  const float* qry = (const float*)d_in[1];
  const float* W1  = (const float*)d_in[2];
  const float* b1  = (const float*)d_in[3];
  const float* W2  = (const float*)d_in[4];
  const float* b2  = (const float*)d_in[5];
  float* out = (float*)d_out;

  char* ws = (char*)d_ws;
  unsigned short* H   = (unsigned short*)(ws);               // 24576*2048*2
  unsigned short* Xbf = (unsigned short*)(ws + 100663296);   // 24576*1024*2
  float* E    = (float*)(ws + 100663296);                    // aliases Xbf (dead after GEMM1)
  unsigned short* W1T = (unsigned short*)(ws + 150994944);
  unsigned short* W2T = (unsigned short*)(ws + 155189248);
  float* Km   = (float*)(ws + 157286400);
  float* eta2 = (float*)(ws + 158334976);
  float* alp  = (float*)(ws + 158336000);
  float* ctr  = (float*)(ws + 158368768);

  castx<<<dim3(2048), dim3(256), 0, stream>>>(sup, qry, Xbf);
  transcast<<<dim3(64, 32), dim3(256), 0, stream>>>(W1, W1T, 1024, 2048);
  transcast<<<dim3(16, 64), dim3(256), 0, stream>>>(W2, W2T, 2048, 512);
  gemm256<1, 1><<<dim3(8, 96), dim3(512), 0, stream>>>(Xbf, W1T, b1, (void*)H, 24576, 2048, 1024);
  gemm256<0, 0><<<dim3(2, 96), dim3(512), 0, stream>>>(H, W2T, b2, (void*)E, 24576, 512, 2048);
  makeK<<<dim3(256), dim3(256), 0, stream>>>(E, Km, eta2);
  qp_kernel<<<dim3(64), dim3(256), 0, stream>>>(Km, eta2, alp);
  centers_k<<<dim3(256), dim3(128), 0, stream>>>(alp, E, ctr);
  logits_k<<<dim3(256), dim3(256), 0, stream>>>(ctr, E, out);
}

// Round 4
// 308.631 us; speedup vs baseline: 1.2820x; 1.0231x over previous
//
#include <hip/hip_runtime.h>
#include <hip/hip_bf16.h>

// ---------- helpers ----------
typedef __attribute__((ext_vector_type(8))) short bf16x8;
typedef __attribute__((ext_vector_type(4))) float f32x4;
typedef __attribute__((ext_vector_type(4))) unsigned short us4;

__device__ __forceinline__ unsigned short bf16_rne(float f) {
  unsigned u = __float_as_uint(f);
  unsigned r = u + 0x7fffu + ((u >> 16) & 1u);
  return (unsigned short)(r >> 16);
}

__device__ __forceinline__ void gload16(const void* g, void* l) {
  typedef const __attribute__((address_space(1))) unsigned int* gas;
  typedef __attribute__((address_space(3))) unsigned int* las;
  __builtin_amdgcn_global_load_lds((gas)g, (las)l, 16, 0, 0);
}

__device__ __forceinline__ float lane_f(float v, int l) {
  return __int_as_float(__builtin_amdgcn_readlane(__float_as_int(v), l));
}

#define BAR() asm volatile("s_barrier" ::: "memory")
#define VMCNT4() asm volatile("s_waitcnt vmcnt(4)" ::: "memory")

// ---------- cast inputs (support+query) f32 -> bf16, flat [24576][1024] ----------
__global__ __launch_bounds__(256) void castx(const float* __restrict__ sup,
                                             const float* __restrict__ qry,
                                             unsigned short* __restrict__ X) {
  const int stride = gridDim.x * blockDim.x;
  for (int i = blockIdx.x * blockDim.x + threadIdx.x; i < 6291456; i += stride) {
    float4 v = (i < 2097152) ? ((const float4*)sup)[i] : ((const float4*)qry)[i - 2097152];
    us4 o = { bf16_rne(v.x), bf16_rne(v.y), bf16_rne(v.z), bf16_rne(v.w) };
    *(us4*)(X + (size_t)i * 4) = o;
  }
}

// ---------- transpose+cast W [R][C] f32 -> WT [C][R] bf16 ----------
__global__ __launch_bounds__(256) void transcast(const float* __restrict__ src,
                                                 unsigned short* __restrict__ dst,
                                                 int R, int C) {
  __shared__ float t[32][33];
  const int tx = threadIdx.x & 31, ty = threadIdx.x >> 5;
  const int c0 = blockIdx.x * 32, r0 = blockIdx.y * 32;
#pragma unroll
  for (int j = 0; j < 4; j++)
    t[ty + j * 8][tx] = src[(size_t)(r0 + ty + j * 8) * C + c0 + tx];
  __syncthreads();
#pragma unroll
  for (int j = 0; j < 4; j++)
    dst[(size_t)(c0 + ty + j * 8) * R + r0 + tx] = bf16_rne(t[tx][ty + j * 8]);
}

// ---------- 256x256 8-phase bf16 GEMM ----------
// Chunks: A0@0, A1@32768, B0@65536, B1@98304 (bytes). K-loop unrolled x2 so
// buffer parity is compile-time; all ds_read addrs = lane-invariant VGPR +
// compile-time immediate (swizzle XOR is per-lane constant: row&7 == l15&7).
#define MFMA_Q(AO, BO, MOFF, NOFF)                                                  \
  __builtin_amdgcn_s_setprio(1);                                                    \
  _Pragma("unroll") for (int i_ = 0; i_ < 4; ++i_)                                  \
  _Pragma("unroll") for (int j_ = 0; j_ < 2; ++j_)                                  \
  _Pragma("unroll") for (int ks_ = 0; ks_ < 2; ++ks_)                               \
    acc[(MOFF) + i_][(NOFF) + j_] = __builtin_amdgcn_mfma_f32_16x16x32_bf16(        \
        AO[i_][ks_], BO[j_][ks_], acc[(MOFF) + i_][(NOFF) + j_], 0, 0, 0);          \
  __builtin_amdgcn_s_setprio(0);

// lane fragment read: base VGPR (vA_/vB_ per ks) + compile-time disp
#define RDA(KS, ACH, MH, I) \
  (*(const bf16x8*)(lsc + ((ACH) * 32768 + (MH) * 8192 + (I) * 2048) + ((KS) ? vA_1 : vA_0)))
#define RDB(KS, BCH, JI) \
  (*(const bf16x8*)(lsc + ((BCH) * 32768 + (JI) * 2048) + ((KS) ? vB_1 : vB_0)))

// stage one 128-row half-tile (2 x gload16/lane): GLP = lane src ptr incl tile off
#define STG(GLP, CHOFF, HALF)                                                     \
  gload16((GLP) + (size_t)((HALF) * 128) * ld,                                    \
          (char*)ls + ((CHOFF) + (HALF) * 16384) + wid * 1024);                   \
  gload16((GLP) + (size_t)((HALF) * 128 + 64) * ld,                               \
          (char*)ls + ((CHOFF) + (HALF) * 16384 + 8192) + wid * 1024);

// one K-tile iteration; ACH/BCH = read chunks (0/1 within A/B), ASO/BSO = stage
// chunk byte offsets; T1/T2 = A-stage tile, B-stage tile indices
#define GITER(ACH, BCH, ASO, BSO, T1, T2)                                         \
  {                                                                               \
    const char* Ap = AgL + (size_t)(T1) * 128;                                    \
    const char* Bp = BgL + (size_t)(T2) * 128;                                    \
    _Pragma("unroll") for (int i = 0; i < 4; ++i) {                               \
      afr[i][0] = RDA(0, ACH, 0, i); afr[i][1] = RDA(1, ACH, 0, i);               \
    }                                                                             \
    _Pragma("unroll") for (int j = 0; j < 2; ++j) {                               \
      bfr0[j][0] = RDB(0, BCH, j); bfr0[j][1] = RDB(1, BCH, j);                   \
    }                                                                             \
    STG(Ap, ASO, 0);                                                              \
    BAR();                                                                        \
    MFMA_Q(afr, bfr0, 0, 0);                                                      \
    BAR();                                                                        \
    _Pragma("unroll") for (int j = 0; j < 2; ++j) {                               \
      bfr1[j][0] = RDB(0, BCH, 2 + j); bfr1[j][1] = RDB(1, BCH, 2 + j);           \
    }                                                                             \
    STG(Ap, ASO, 1);                                                              \
    BAR();                                                                        \
    MFMA_Q(afr, bfr1, 0, 2);                                                      \
    BAR();                                                                        \
    _Pragma("unroll") for (int i = 0; i < 4; ++i) {                               \
      afr[i][0] = RDA(0, ACH, 1, i); afr[i][1] = RDA(1, ACH, 1, i);               \
    }                                                                             \
    STG(Bp, BSO, 0);                                                              \
    BAR();                                                                        \
    MFMA_Q(afr, bfr1, 4, 2);                                                      \
    BAR();                                                                        \
    STG(Bp, BSO, 1);                                                              \
    VMCNT4();                                                                     \
    BAR();                                                                        \
    MFMA_Q(afr, bfr0, 4, 0);                                                      \
    BAR();                                                                        \
  }

template <int ACT, int OUTBF>
__global__ __launch_bounds__(512) void gemm256(const unsigned short* __restrict__ A,
                                               const unsigned short* __restrict__ BT,
                                               const float* __restrict__ bias,
                                               void* __restrict__ Cout,
                                               int M, int N, int K) {
  __shared__ __attribute__((aligned(16))) short ls[4][16384];  // A0,A1,B0,B1
  const int tid = threadIdx.x, lane = tid & 63, wid = tid >> 6;
  const int wm = wid >> 2, wn = wid & 3;
  const int l15 = lane & 15, lg = lane >> 4;

  // bijective XCD swizzle (nwg % 8 == 0 for both GEMMs)
  int lin = blockIdx.y * gridDim.x + blockIdx.x;
  int nwg = gridDim.x * gridDim.y;
  int swz = (lin & 7) * (nwg >> 3) + (lin >> 3);
  int bx = swz % gridDim.x, by = swz / gridDim.x;
  const int m0 = by * 256, n0 = bx * 256;

  const size_t ld = (size_t)K * 2;
  const char* Ag = (const char*)A + (size_t)m0 * ld;
  const char* Bg = (const char*)BT + (size_t)n0 * ld;
  const int NT = K >> 6;
  const char* lsc = (const char*)ls;

  // per-lane invariant LDS read bases (swizzle XOR folded; two per ks since the
  // XOR touches bit6 and ks*64 must be inside the XOR, not added after)
  const int swz4 = (l15 & 7) << 4;
  const int bk0 = (l15 * 128 + lg * 16) ^ swz4;
  const int bk1 = (l15 * 128 + 64 + lg * 16) ^ swz4;
  const int vA_0 = bk0 + wm * 16384, vA_1 = bk1 + wm * 16384;
  const int vB_0 = bk0 + wn * 8192 + 65536, vB_1 = bk1 + wn * 8192 + 65536;

  // per-lane invariant global staging source (pre-swizzled column)
  const int srcrow = wid * 8 + (lane >> 3);
  const int kperm = ((lane & 7) ^ (lane >> 3)) << 4;
  const char* AgL = Ag + (size_t)srcrow * ld + kperm;
  const char* BgL = Bg + (size_t)srcrow * ld + kperm;

  f32x4 acc[8][4] = {};
  bf16x8 afr[4][2], bfr0[2][2], bfr1[2][2];

  // prologue: A t0 -> A0, B t0 -> B0, B t1 -> B1; wait through tile0
  STG(AgL, 0, 0); STG(AgL, 0, 1);
  STG(BgL, 65536, 0); STG(BgL, 65536, 1);
  STG(BgL + 128, 98304, 0); STG(BgL + 128, 98304, 1);
  VMCNT4();
  BAR();

  for (int u = 0; u < NT; u += 2) {
    int t2a = u + 2; if (t2a >= NT) t2a = 0;
    GITER(0, 0, 32768, 65536, u + 1, t2a);        // even tile: rd A0,B0; st A1,B0
    int t1b = u + 2; if (t1b >= NT) t1b = 0;
    int t2b = u + 3; if (t2b >= NT) t2b -= NT;
    GITER(1, 1, 0, 98304, t1b, t2b);              // odd tile: rd A1,B1; st A0,B1
  }

  float bv[4];
#pragma unroll
  for (int nf = 0; nf < 4; ++nf) bv[nf] = bias[n0 + wn * 64 + nf * 16 + l15];
#pragma unroll
  for (int mf = 0; mf < 8; ++mf) {
    int rbase = m0 + wm * 128 + mf * 16 + lg * 4;
#pragma unroll
    for (int nf = 0; nf < 4; ++nf) {
      int col = n0 + wn * 64 + nf * 16 + l15;
#pragma unroll
      for (int j = 0; j < 4; ++j) {
        float v = acc[mf][nf][j] + bv[nf];
        if (ACT) v = v > 0.f ? v : 0.f;
        size_t idx = (size_t)(rbase + j) * N + col;
        if (OUTBF) ((unsigned short*)Cout)[idx] = bf16_rne(v);
        else       ((float*)Cout)[idx] = v;
      }
    }
  }
}

// ---------- per-task K = Es Es^T + eps*I, eta2 = log2(e)/(2*max row abs-sum) ----------
__global__ __launch_bounds__(256) void makeK(const float* __restrict__ E,
                                             float* __restrict__ Km,
                                             float* __restrict__ eta2v) {
  __shared__ float es[32][512];  // 64 KB
  const int b = blockIdx.x, tid = threadIdx.x;
  const float4* Eb = (const float4*)(E + (size_t)b * 32 * 512);
  float4* es4 = (float4*)&es[0][0];
  for (int i = tid; i < 32 * 128; i += 256) es4[i] = Eb[i];
  __syncthreads();

  const int s = tid >> 3, tq = tid & 7;
  const float4* rs4 = (const float4*)&es[s][0];
  const float4* rt0 = (const float4*)&es[tq * 4 + 0][0];
  const float4* rt1 = (const float4*)&es[tq * 4 + 1][0];
  const float4* rt2 = (const float4*)&es[tq * 4 + 2][0];
  const float4* rt3 = (const float4*)&es[tq * 4 + 3][0];
  float4 a0 = {0, 0, 0, 0}, a1 = {0, 0, 0, 0}, a2 = {0, 0, 0, 0}, a3 = {0, 0, 0, 0};
  for (int dd = 0; dd < 128; ++dd) {
    float4 av = rs4[dd];
    float4 b0 = rt0[dd], b1 = rt1[dd], b2 = rt2[dd], b3 = rt3[dd];
    a0.x = fmaf(av.x, b0.x, a0.x); a0.y = fmaf(av.y, b0.y, a0.y);
    a0.z = fmaf(av.z, b0.z, a0.z); a0.w = fmaf(av.w, b0.w, a0.w);
    a1.x = fmaf(av.x, b1.x, a1.x); a1.y = fmaf(av.y, b1.y, a1.y);
    a1.z = fmaf(av.z, b1.z, a1.z); a1.w = fmaf(av.w, b1.w, a1.w);
    a2.x = fmaf(av.x, b2.x, a2.x); a2.y = fmaf(av.y, b2.y, a2.y);
    a2.z = fmaf(av.z, b2.z, a2.z); a2.w = fmaf(av.w, b2.w, a2.w);
    a3.x = fmaf(av.x, b3.x, a3.x); a3.y = fmaf(av.y, b3.y, a3.y);
    a3.z = fmaf(av.z, b3.z, a3.z); a3.w = fmaf(av.w, b3.w, a3.w);
  }
  float kv[4] = { (a0.x + a0.y) + (a0.z + a0.w), (a1.x + a1.y) + (a1.z + a1.w),
                  (a2.x + a2.y) + (a2.z + a2.w), (a3.x + a3.y) + (a3.z + a3.w) };
  float p = 0.f;
#pragma unroll
  for (int j = 0; j < 4; j++) {
    if (s == tq * 4 + j) kv[j] += 1e-6f;
    p += fabsf(kv[j]);
    Km[(size_t)b * 1024 + s * 32 + tq * 4 + j] = kv[j];
  }
  p += __shfl_xor(p, 1); p += __shfl_xor(p, 2); p += __shfl_xor(p, 4);
  __syncthreads();
  float* rs = &es[0][0];
  if (tq == 0) rs[s] = p;
  __syncthreads();
  if (tid < 32) {
    float m = rs[tid];
    m = fmaxf(m, __shfl_xor(m, 1));
    m = fmaxf(m, __shfl_xor(m, 2));
    m = fmaxf(m, __shfl_xor(m, 4));
    m = fmaxf(m, __shfl_xor(m, 8));
    m = fmaxf(m, __shfl_xor(m, 16));
    if (tid == 0) eta2v[b] = 1.4426950408889634f / (2.0f * m);
  }
}

// ---------- QP: 500 EG iterations in unnormalized w-space, one wave per task ----------
__global__ __launch_bounds__(256) void qp_kernel(const float* __restrict__ Km,
                                                 const float* __restrict__ eta2v,
                                                 float* __restrict__ alp) {
  const int lane = threadIdx.x & 63, wid = threadIdx.x >> 6;
  const int b = blockIdx.x * 4 + wid;
  const int s = lane & 31;
  const float* Kb = Km + (size_t)b * 1024;
  float kr[32];
#pragma unroll
  for (int i = 0; i < 8; i++) {
    float4 v = ((const float4*)(Kb + s * 32))[i];
    kr[i * 4 + 0] = v.x; kr[i * 4 + 1] = v.y; kr[i * 4 + 2] = v.z; kr[i * 4 + 3] = v.w;
  }
  const float kd = Kb[s * 33];
  const float eta2 = eta2v[b];
  const float c2 = eta2 * kd;
  const float m2n = -2.0f * eta2;
  float w = 0.03125f;
  for (int it = 0; it < 500; ++it) {
    float c0 = 0.f, c1 = 0.f, ca = 0.f, c3 = 0.f;
#pragma unroll
    for (int t = 0; t < 32; t += 4) {
      c0 = fmaf(kr[t + 0], lane_f(w, t + 0), c0);
      c1 = fmaf(kr[t + 1], lane_f(w, t + 1), c1);
      ca = fmaf(kr[t + 2], lane_f(w, t + 2), ca);
      c3 = fmaf(kr[t + 3], lane_f(w, t + 3), c3);
    }
    float tK = (c0 + c1) + (ca + c3);
    float r = w;
    r += __int_as_float(__builtin_amdgcn_update_dpp(0, __float_as_int(r), 0x128, 0xf, 0xf, true));
    r += __int_as_float(__builtin_amdgcn_update_dpp(0, __float_as_int(r), 0x124, 0xf, 0xf, true));
    r += __int_as_float(__builtin_amdgcn_update_dpp(0, __float_as_int(r), 0x122, 0xf, 0xf, true));
    r += __int_as_float(__builtin_amdgcn_update_dpp(0, __float_as_int(r), 0x121, 0xf, 0xf, true));
    r += __shfl_xor(r, 16);
    float R = __builtin_amdgcn_rcpf(r);
    float z = fmaf(m2n * R, tK, c2);
    w = w * R * __builtin_amdgcn_exp2f(z);
  }
  float r = w;
  r += __int_as_float(__builtin_amdgcn_update_dpp(0, __float_as_int(r), 0x128, 0xf, 0xf, true));
  r += __int_as_float(__builtin_amdgcn_update_dpp(0, __float_as_int(r), 0x124, 0xf, 0xf, true));
  r += __int_as_float(__builtin_amdgcn_update_dpp(0, __float_as_int(r), 0x122, 0xf, 0xf, true));
  r += __int_as_float(__builtin_amdgcn_update_dpp(0, __float_as_int(r), 0x121, 0xf, 0xf, true));
  r += __shfl_xor(r, 16);
  float R = __builtin_amdgcn_rcpf(r);
  if (lane < 32) alp[(size_t)b * 32 + s] = w * R;
}

// ---------- centers[b] = sum_s alpha[b][s] * Es[b][s][:] ----------
__global__ __launch_bounds__(128) void centers_k(const float* __restrict__ alp,
                                                 const float* __restrict__ E,
                                                 float* __restrict__ ctr) {
  const int b = blockIdx.x, t = threadIdx.x;
  __shared__ float av[32];
  if (t < 32) av[t] = alp[(size_t)b * 32 + t];
  __syncthreads();
  const float4* Eb = (const float4*)(E + (size_t)b * 32 * 512);
  float4 c = {0, 0, 0, 0};
#pragma unroll 8
  for (int sIdx = 0; sIdx < 32; sIdx++) {
    float a = av[sIdx];
    float4 v = Eb[sIdx * 128 + t];
    c.x = fmaf(a, v.x, c.x); c.y = fmaf(a, v.y, c.y);
    c.z = fmaf(a, v.z, c.z); c.w = fmaf(a, v.w, c.w);
  }
  ((float4*)ctr)[b * 128 + t] = c;
}

// ---------- logits[b][q] = -||center[b] - Eq[b][q]||^2 ----------
__global__ __launch_bounds__(256) void logits_k(const float* __restrict__ ctr,
                                                const float* __restrict__ E,
                                                float* __restrict__ out) {
  const int b = blockIdx.x, lane = threadIdx.x & 63, w = threadIdx.x >> 6;
  const float4* C4 = (const float4*)(ctr + (size_t)b * 512);
  const float4 cA = C4[lane * 2], cB = C4[lane * 2 + 1];
  const float4* Q4 = (const float4*)(E + (size_t)(8192 + b * 64) * 512);
  for (int q = w; q < 64; q += 4) {
    float4 e0 = Q4[(size_t)q * 128 + lane * 2];
    float4 e1 = Q4[(size_t)q * 128 + lane * 2 + 1];
    float d, ss = 0.f;
    d = cA.x - e0.x; ss = fmaf(d, d, ss);
    d = cA.y - e0.y; ss = fmaf(d, d, ss);
    d = cA.z - e0.z; ss = fmaf(d, d, ss);
    d = cA.w - e0.w; ss = fmaf(d, d, ss);
    d = cB.x - e1.x; ss = fmaf(d, d, ss);
    d = cB.y - e1.y; ss = fmaf(d, d, ss);
    d = cB.z - e1.z; ss = fmaf(d, d, ss);
    d = cB.w - e1.w; ss = fmaf(d, d, ss);
    ss += __shfl_xor(ss, 1);  ss += __shfl_xor(ss, 2);  ss += __shfl_xor(ss, 4);
    ss += __shfl_xor(ss, 8);  ss += __shfl_xor(ss, 16); ss += __shfl_xor(ss, 32);
    if (lane == 0) out[b * 64 + q] = -ss;
  }
}

// ---------- launch ----------
extern "C" void kernel_launch(void* const* d_in, const int* in_sizes, int n_in,
                              void* d_out, int out_size, void* d_ws, size_t ws_size,
                              hipStream_t stream) {
  const float* sup = (const float*)d_in[0];
  const float* qry = (const float*)d_in[1];
  const float* W1  = (const float*)d_in[2];
  const float* b1  = (const float*)d_in[3];
  const float* W2  = (const float*)d_in[4];
  const float* b2  = (const float*)d_in[5];
  float* out = (float*)d_out;

  char* ws = (char*)d_ws;
  unsigned short* H   = (unsigned short*)(ws);               // 24576*2048*2
  unsigned short* Xbf = (unsigned short*)(ws + 100663296);   // 24576*1024*2
  float* E    = (float*)(ws + 100663296);                    // aliases Xbf (dead after GEMM1)
  unsigned short* W1T = (unsigned short*)(ws + 150994944);
  unsigned short* W2T = (unsigned short*)(ws + 155189248);
  float* Km   = (float*)(ws + 157286400);
  float* eta2 = (float*)(ws + 158334976);
  float* alp  = (float*)(ws + 158336000);
  float* ctr  = (float*)(ws + 158368768);

  castx<<<dim3(2048), dim3(256), 0, stream>>>(sup, qry, Xbf);
  transcast<<<dim3(64, 32), dim3(256), 0, stream>>>(W1, W1T, 1024, 2048);
  transcast<<<dim3(16, 64), dim3(256), 0, stream>>>(W2, W2T, 2048, 512);
  gemm256<1, 1><<<dim3(8, 96), dim3(512), 0, stream>>>(Xbf, W1T, b1, (void*)H, 24576, 2048, 1024);
  gemm256<0, 0><<<dim3(2, 96), dim3(512), 0, stream>>>(H, W2T, b2, (void*)E, 24576, 512, 2048);
  makeK<<<dim3(256), dim3(256), 0, stream>>>(E, Km, eta2);
  qp_kernel<<<dim3(64), dim3(256), 0, stream>>>(Km, eta2, alp);
  centers_k<<<dim3(256), dim3(128), 0, stream>>>(alp, E, ctr);
  logits_k<<<dim3(256), dim3(256), 0, stream>>>(ctr, E, out);
}

// Round 5
// 303.472 us; speedup vs baseline: 1.3037x; 1.0170x over previous
//
#include <hip/hip_runtime.h>
#include <hip/hip_bf16.h>

// ---------- helpers ----------
typedef __attribute__((ext_vector_type(8))) short bf16x8;
typedef __attribute__((ext_vector_type(4))) float f32x4;
typedef __attribute__((ext_vector_type(4))) unsigned short us4;

__device__ __forceinline__ unsigned short bf16_rne(float f) {
  unsigned u = __float_as_uint(f);
  unsigned r = u + 0x7fffu + ((u >> 16) & 1u);
  return (unsigned short)(r >> 16);
}

__device__ __forceinline__ void gload16(const void* g, void* l) {
  typedef const __attribute__((address_space(1))) unsigned int* gas;
  typedef __attribute__((address_space(3))) unsigned int* las;
  __builtin_amdgcn_global_load_lds((gas)g, (las)l, 16, 0, 0);
}

__device__ __forceinline__ float lane_f(float v, int l) {
  return __int_as_float(__builtin_amdgcn_readlane(__float_as_int(v), l));
}

#define BAR() asm volatile("s_barrier" ::: "memory")
#define VMCNT0() asm volatile("s_waitcnt vmcnt(0)" ::: "memory")
#define LGKM4() asm volatile("s_waitcnt lgkmcnt(4)" ::: "memory")
#define LGKM0() asm volatile("s_waitcnt lgkmcnt(0)" ::: "memory")
#define SB() __builtin_amdgcn_sched_barrier(0)

// ---------- cast inputs (support+query) f32 -> bf16, flat [24576][1024] ----------
__global__ __launch_bounds__(256) void castx(const float* __restrict__ sup,
                                             const float* __restrict__ qry,
                                             unsigned short* __restrict__ X) {
  const int stride = gridDim.x * blockDim.x;
  for (int i = blockIdx.x * blockDim.x + threadIdx.x; i < 6291456; i += stride) {
    float4 v = (i < 2097152) ? ((const float4*)sup)[i] : ((const float4*)qry)[i - 2097152];
    us4 o = { bf16_rne(v.x), bf16_rne(v.y), bf16_rne(v.z), bf16_rne(v.w) };
    *(us4*)(X + (size_t)i * 4) = o;
  }
}

// ---------- transpose+cast W [R][C] f32 -> WT [C][R] bf16 ----------
__global__ __launch_bounds__(256) void transcast(const float* __restrict__ src,
                                                 unsigned short* __restrict__ dst,
                                                 int R, int C) {
  __shared__ float t[32][33];
  const int tx = threadIdx.x & 31, ty = threadIdx.x >> 5;
  const int c0 = blockIdx.x * 32, r0 = blockIdx.y * 32;
#pragma unroll
  for (int j = 0; j < 4; j++)
    t[ty + j * 8][tx] = src[(size_t)(r0 + ty + j * 8) * C + c0 + tx];
  __syncthreads();
#pragma unroll
  for (int j = 0; j < 4; j++)
    dst[(size_t)(c0 + ty + j * 8) * R + r0 + tx] = bf16_rne(t[tx][ty + j * 8]);
}

// ---------- 256x256 bf16 GEMM, 1-barrier-per-K-tile pipeline ----------
// Chunks: A0@0, A1@32768, B0@65536, B1@98304 (bytes). Double-buffered, staged
// 1 tile ahead. Per tile: vmcnt(0)+barrier (collective "staging landed & reads
// drained"), batch ds_reads, batch staging gloads, MFMA quarters gated by
// counted lgkmcnt + sched_barrier(0) (rule #18). One barrier per K-tile ->
// the 2 waves/SIMD skew phases so ds_reads hide under the other wave's MFMA.
#define MFMA_Q(AO, BO, MOFF, NOFF)                                                  \
  __builtin_amdgcn_s_setprio(1);                                                    \
  _Pragma("unroll") for (int i_ = 0; i_ < 4; ++i_)                                  \
  _Pragma("unroll") for (int j_ = 0; j_ < 2; ++j_)                                  \
  _Pragma("unroll") for (int ks_ = 0; ks_ < 2; ++ks_)                               \
    acc[(MOFF) + i_][(NOFF) + j_] = __builtin_amdgcn_mfma_f32_16x16x32_bf16(        \
        AO[i_][ks_], BO[j_][ks_], acc[(MOFF) + i_][(NOFF) + j_], 0, 0, 0);          \
  __builtin_amdgcn_s_setprio(0);

// lane fragment read: base VGPR (vA_/vB_ per ks) + compile-time disp
#define RDA(KS, ACH, MH, I) \
  (*(const bf16x8*)(lsc + ((ACH) * 32768 + (MH) * 8192 + (I) * 2048) + ((KS) ? vA_1 : vA_0)))
#define RDB(KS, BCH, JI) \
  (*(const bf16x8*)(lsc + ((BCH) * 32768 + (JI) * 2048) + ((KS) ? vB_1 : vB_0)))

// stage one 128-row half-tile (2 x gload16/lane)
#define STG(GLP, CHOFF, HALF)                                                     \
  gload16((GLP) + (size_t)((HALF) * 128) * ld,                                    \
          (char*)ls + ((CHOFF) + (HALF) * 16384) + wid * 1024);                   \
  gload16((GLP) + (size_t)((HALF) * 128 + 64) * ld,                               \
          (char*)ls + ((CHOFF) + (HALF) * 16384 + 8192) + wid * 1024);

// one K-tile: read chunks (ACH,BCH), stage tile T into the other chunk pair
#define TILE(ACH, BCH, ASO, BSO, T)                                               \
  {                                                                               \
    VMCNT0();                                                                     \
    BAR();                                                                        \
    _Pragma("unroll") for (int i = 0; i < 4; ++i) {                               \
      afr[i][0] = RDA(0, ACH, 0, i); afr[i][1] = RDA(1, ACH, 0, i);               \
    }                                                                             \
    _Pragma("unroll") for (int j = 0; j < 2; ++j) {                               \
      bfr0[j][0] = RDB(0, BCH, j); bfr0[j][1] = RDB(1, BCH, j);                   \
    }                                                                             \
    _Pragma("unroll") for (int j = 0; j < 2; ++j) {                               \
      bfr1[j][0] = RDB(0, BCH, 2 + j); bfr1[j][1] = RDB(1, BCH, 2 + j);           \
    }                                                                             \
    const char* Ap_ = AgL + (size_t)(T) * 128;                                    \
    const char* Bp_ = BgL + (size_t)(T) * 128;                                    \
    STG(Ap_, ASO, 0); STG(Ap_, ASO, 1);                                           \
    STG(Bp_, BSO, 0); STG(Bp_, BSO, 1);                                           \
    LGKM4(); SB();                                                                \
    MFMA_Q(afr, bfr0, 0, 0);                                                      \
    LGKM0(); SB();                                                                \
    MFMA_Q(afr, bfr1, 0, 2);                                                      \
    _Pragma("unroll") for (int i = 0; i < 4; ++i) {                               \
      afr[i][0] = RDA(0, ACH, 1, i); afr[i][1] = RDA(1, ACH, 1, i);               \
    }                                                                             \
    LGKM0(); SB();                                                                \
    MFMA_Q(afr, bfr1, 4, 2);                                                      \
    MFMA_Q(afr, bfr0, 4, 0);                                                      \
  }

template <int ACT, int OUTBF>
__global__ __launch_bounds__(512) void gemm256(const unsigned short* __restrict__ A,
                                               const unsigned short* __restrict__ BT,
                                               const float* __restrict__ bias,
                                               void* __restrict__ Cout,
                                               int M, int N, int K) {
  __shared__ __attribute__((aligned(16))) short ls[4][16384];  // A0,A1,B0,B1
  const int tid = threadIdx.x, lane = tid & 63, wid = tid >> 6;
  const int wm = wid >> 2, wn = wid & 3;
  const int l15 = lane & 15, lg = lane >> 4;

  // bijective XCD swizzle (nwg % 8 == 0 for both GEMMs)
  int lin = blockIdx.y * gridDim.x + blockIdx.x;
  int nwg = gridDim.x * gridDim.y;
  int swz = (lin & 7) * (nwg >> 3) + (lin >> 3);
  int bx = swz % gridDim.x, by = swz / gridDim.x;
  const int m0 = by * 256, n0 = bx * 256;

  const size_t ld = (size_t)K * 2;
  const char* Ag = (const char*)A + (size_t)m0 * ld;
  const char* Bg = (const char*)BT + (size_t)n0 * ld;
  const int NT = K >> 6;
  const char* lsc = (const char*)ls;

  // per-lane invariant LDS read bases (swizzle XOR folded; two per ks since the
  // XOR touches bit6 and ks*64 must be inside the XOR, not added after)
  const int swz4 = (l15 & 7) << 4;
  const int bk0 = (l15 * 128 + lg * 16) ^ swz4;
  const int bk1 = (l15 * 128 + 64 + lg * 16) ^ swz4;
  const int vA_0 = bk0 + wm * 16384, vA_1 = bk1 + wm * 16384;
  const int vB_0 = bk0 + wn * 8192 + 65536, vB_1 = bk1 + wn * 8192 + 65536;

  // per-lane invariant global staging source (pre-swizzled column)
  const int srcrow = wid * 8 + (lane >> 3);
  const int kperm = ((lane & 7) ^ (lane >> 3)) << 4;
  const char* AgL = Ag + (size_t)srcrow * ld + kperm;
  const char* BgL = Bg + (size_t)srcrow * ld + kperm;

  f32x4 acc[8][4] = {};
  bf16x8 afr[4][2], bfr0[2][2], bfr1[2][2];

  // prologue: tile 0 -> A0,B0
  STG(AgL, 0, 0); STG(AgL, 0, 1);
  STG(BgL, 65536, 0); STG(BgL, 65536, 1);

  for (int u = 0; u < NT; u += 2) {
    int t1 = u + 1;                       // < NT (NT even)
    int t2 = u + 2; if (t2 >= NT) t2 = 0; // wrap: harmless redundant prefetch
    TILE(0, 0, 32768, 98304, t1);         // read A0,B0; stage t1 -> A1,B1
    TILE(1, 1, 0, 65536, t2);             // read A1,B1; stage t2 -> A0,B0
  }

  float bv[4];
#pragma unroll
  for (int nf = 0; nf < 4; ++nf) bv[nf] = bias[n0 + wn * 64 + nf * 16 + l15];
#pragma unroll
  for (int mf = 0; mf < 8; ++mf) {
    int rbase = m0 + wm * 128 + mf * 16 + lg * 4;
#pragma unroll
    for (int nf = 0; nf < 4; ++nf) {
      int col = n0 + wn * 64 + nf * 16 + l15;
#pragma unroll
      for (int j = 0; j < 4; ++j) {
        float v = acc[mf][nf][j] + bv[nf];
        if (ACT) v = v > 0.f ? v : 0.f;
        size_t idx = (size_t)(rbase + j) * N + col;
        if (OUTBF) ((unsigned short*)Cout)[idx] = bf16_rne(v);
        else       ((float*)Cout)[idx] = v;
      }
    }
  }
}

// ---------- per-task K = Es Es^T + eps*I, eta2 = log2(e)/(2*max row abs-sum) ----------
__global__ __launch_bounds__(256) void makeK(const float* __restrict__ E,
                                             float* __restrict__ Km,
                                             float* __restrict__ eta2v) {
  __shared__ float es[32][512];  // 64 KB
  const int b = blockIdx.x, tid = threadIdx.x;
  const float4* Eb = (const float4*)(E + (size_t)b * 32 * 512);
  float4* es4 = (float4*)&es[0][0];
  for (int i = tid; i < 32 * 128; i += 256) es4[i] = Eb[i];
  __syncthreads();

  const int s = tid >> 3, tq = tid & 7;
  const float4* rs4 = (const float4*)&es[s][0];
  const float4* rt0 = (const float4*)&es[tq * 4 + 0][0];
  const float4* rt1 = (const float4*)&es[tq * 4 + 1][0];
  const float4* rt2 = (const float4*)&es[tq * 4 + 2][0];
  const float4* rt3 = (const float4*)&es[tq * 4 + 3][0];
  float4 a0 = {0, 0, 0, 0}, a1 = {0, 0, 0, 0}, a2 = {0, 0, 0, 0}, a3 = {0, 0, 0, 0};
  for (int dd = 0; dd < 128; ++dd) {
    float4 av = rs4[dd];
    float4 b0 = rt0[dd], b1 = rt1[dd], b2 = rt2[dd], b3 = rt3[dd];
    a0.x = fmaf(av.x, b0.x, a0.x); a0.y = fmaf(av.y, b0.y, a0.y);
    a0.z = fmaf(av.z, b0.z, a0.z); a0.w = fmaf(av.w, b0.w, a0.w);
    a1.x = fmaf(av.x, b1.x, a1.x); a1.y = fmaf(av.y, b1.y, a1.y);
    a1.z = fmaf(av.z, b1.z, a1.z); a1.w = fmaf(av.w, b1.w, a1.w);
    a2.x = fmaf(av.x, b2.x, a2.x); a2.y = fmaf(av.y, b2.y, a2.y);
    a2.z = fmaf(av.z, b2.z, a2.z); a2.w = fmaf(av.w, b2.w, a2.w);
    a3.x = fmaf(av.x, b3.x, a3.x); a3.y = fmaf(av.y, b3.y, a3.y);
    a3.z = fmaf(av.z, b3.z, a3.z); a3.w = fmaf(av.w, b3.w, a3.w);
  }
  float kv[4] = { (a0.x + a0.y) + (a0.z + a0.w), (a1.x + a1.y) + (a1.z + a1.w),
                  (a2.x + a2.y) + (a2.z + a2.w), (a3.x + a3.y) + (a3.z + a3.w) };
  float p = 0.f;
#pragma unroll
  for (int j = 0; j < 4; j++) {
    if (s == tq * 4 + j) kv[j] += 1e-6f;
    p += fabsf(kv[j]);
    Km[(size_t)b * 1024 + s * 32 + tq * 4 + j] = kv[j];
  }
  p += __shfl_xor(p, 1); p += __shfl_xor(p, 2); p += __shfl_xor(p, 4);
  __syncthreads();
  float* rs = &es[0][0];
  if (tq == 0) rs[s] = p;
  __syncthreads();
  if (tid < 32) {
    float m = rs[tid];
    m = fmaxf(m, __shfl_xor(m, 1));
    m = fmaxf(m, __shfl_xor(m, 2));
    m = fmaxf(m, __shfl_xor(m, 4));
    m = fmaxf(m, __shfl_xor(m, 8));
    m = fmaxf(m, __shfl_xor(m, 16));
    if (tid == 0) eta2v[b] = 1.4426950408889634f / (2.0f * m);
  }
}

// ---------- QP: 500 EG iterations in unnormalized w-space, one wave per task ----------
__global__ __launch_bounds__(256) void qp_kernel(const float* __restrict__ Km,
                                                 const float* __restrict__ eta2v,
                                                 float* __restrict__ alp) {
  const int lane = threadIdx.x & 63, wid = threadIdx.x >> 6;
  const int b = blockIdx.x * 4 + wid;
  const int s = lane & 31;
  const float* Kb = Km + (size_t)b * 1024;
  float kr[32];
#pragma unroll
  for (int i = 0; i < 8; i++) {
    float4 v = ((const float4*)(Kb + s * 32))[i];
    kr[i * 4 + 0] = v.x; kr[i * 4 + 1] = v.y; kr[i * 4 + 2] = v.z; kr[i * 4 + 3] = v.w;
  }
  const float kd = Kb[s * 33];
  const float eta2 = eta2v[b];
  const float c2 = eta2 * kd;
  const float m2n = -2.0f * eta2;
  float w = 0.03125f;
  for (int it = 0; it < 500; ++it) {
    float c0 = 0.f, c1 = 0.f, ca = 0.f, c3 = 0.f;
#pragma unroll
    for (int t = 0; t < 32; t += 4) {
      c0 = fmaf(kr[t + 0], lane_f(w, t + 0), c0);
      c1 = fmaf(kr[t + 1], lane_f(w, t + 1), c1);
      ca = fmaf(kr[t + 2], lane_f(w, t + 2), ca);
      c3 = fmaf(kr[t + 3], lane_f(w, t + 3), c3);
    }
    float tK = (c0 + c1) + (ca + c3);
    float r = w;
    r += __int_as_float(__builtin_amdgcn_update_dpp(0, __float_as_int(r), 0x128, 0xf, 0xf, true));
    r += __int_as_float(__builtin_amdgcn_update_dpp(0, __float_as_int(r), 0x124, 0xf, 0xf, true));
    r += __int_as_float(__builtin_amdgcn_update_dpp(0, __float_as_int(r), 0x122, 0xf, 0xf, true));
    r += __int_as_float(__builtin_amdgcn_update_dpp(0, __float_as_int(r), 0x121, 0xf, 0xf, true));
    r += __shfl_xor(r, 16);
    float R = __builtin_amdgcn_rcpf(r);
    float z = fmaf(m2n * R, tK, c2);
    w = w * R * __builtin_amdgcn_exp2f(z);
  }
  float r = w;
  r += __int_as_float(__builtin_amdgcn_update_dpp(0, __float_as_int(r), 0x128, 0xf, 0xf, true));
  r += __int_as_float(__builtin_amdgcn_update_dpp(0, __float_as_int(r), 0x124, 0xf, 0xf, true));
  r += __int_as_float(__builtin_amdgcn_update_dpp(0, __float_as_int(r), 0x122, 0xf, 0xf, true));
  r += __int_as_float(__builtin_amdgcn_update_dpp(0, __float_as_int(r), 0x121, 0xf, 0xf, true));
  r += __shfl_xor(r, 16);
  float R = __builtin_amdgcn_rcpf(r);
  if (lane < 32) alp[(size_t)b * 32 + s] = w * R;
}

// ---------- centers[b] = sum_s alpha[b][s] * Es[b][s][:] ----------
__global__ __launch_bounds__(128) void centers_k(const float* __restrict__ alp,
                                                 const float* __restrict__ E,
                                                 float* __restrict__ ctr) {
  const int b = blockIdx.x, t = threadIdx.x;
  __shared__ float av[32];
  if (t < 32) av[t] = alp[(size_t)b * 32 + t];
  __syncthreads();
  const float4* Eb = (const float4*)(E + (size_t)b * 32 * 512);
  float4 c = {0, 0, 0, 0};
#pragma unroll 8
  for (int sIdx = 0; sIdx < 32; sIdx++) {
    float a = av[sIdx];
    float4 v = Eb[sIdx * 128 + t];
    c.x = fmaf(a, v.x, c.x); c.y = fmaf(a, v.y, c.y);
    c.z = fmaf(a, v.z, c.z); c.w = fmaf(a, v.w, c.w);
  }
  ((float4*)ctr)[b * 128 + t] = c;
}

// ---------- logits[b][q] = -||center[b] - Eq[b][q]||^2 ----------
__global__ __launch_bounds__(256) void logits_k(const float* __restrict__ ctr,
                                                const float* __restrict__ E,
                                                float* __restrict__ out) {
  const int b = blockIdx.x, lane = threadIdx.x & 63, w = threadIdx.x >> 6;
  const float4* C4 = (const float4*)(ctr + (size_t)b * 512);
  const float4 cA = C4[lane * 2], cB = C4[lane * 2 + 1];
  const float4* Q4 = (const float4*)(E + (size_t)(8192 + b * 64) * 512);
  for (int q = w; q < 64; q += 4) {
    float4 e0 = Q4[(size_t)q * 128 + lane * 2];
    float4 e1 = Q4[(size_t)q * 128 + lane * 2 + 1];
    float d, ss = 0.f;
    d = cA.x - e0.x; ss = fmaf(d, d, ss);
    d = cA.y - e0.y; ss = fmaf(d, d, ss);
    d = cA.z - e0.z; ss = fmaf(d, d, ss);
    d = cA.w - e0.w; ss = fmaf(d, d, ss);
    d = cB.x - e1.x; ss = fmaf(d, d, ss);
    d = cB.y - e1.y; ss = fmaf(d, d, ss);
    d = cB.z - e1.z; ss = fmaf(d, d, ss);
    d = cB.w - e1.w; ss = fmaf(d, d, ss);
    ss += __shfl_xor(ss, 1);  ss += __shfl_xor(ss, 2);  ss += __shfl_xor(ss, 4);
    ss += __shfl_xor(ss, 8);  ss += __shfl_xor(ss, 16); ss += __shfl_xor(ss, 32);
    if (lane == 0) out[b * 64 + q] = -ss;
  }
}

// ---------- launch ----------
extern "C" void kernel_launch(void* const* d_in, const int* in_sizes, int n_in,
                              void* d_out, int out_size, void* d_ws, size_t ws_size,
                              hipStream_t stream) {
  const float* sup = (const float*)d_in[0];
  const float* qry = (const float*)d_in[1];
  const float* W1  = (const float*)d_in[2];
  const float* b1  = (const float*)d_in[3];
  const float* W2  = (const float*)d_in[4];
  const float* b2  = (const float*)d_in[5];
  float* out = (float*)d_out;

  char* ws = (char*)d_ws;
  unsigned short* H   = (unsigned short*)(ws);               // 24576*2048*2
  unsigned short* Xbf = (unsigned short*)(ws + 100663296);   // 24576*1024*2
  float* E    = (float*)(ws + 100663296);                    // aliases Xbf (dead after GEMM1)
  unsigned short* W1T = (unsigned short*)(ws + 150994944);
  unsigned short* W2T = (unsigned short*)(ws + 155189248);
  float* Km   = (float*)(ws + 157286400);
  float* eta2 = (float*)(ws + 158334976);
  float* alp  = (float*)(ws + 158336000);
  float* ctr  = (float*)(ws + 158368768);

  castx<<<dim3(2048), dim3(256), 0, stream>>>(sup, qry, Xbf);
  transcast<<<dim3(64, 32), dim3(256), 0, stream>>>(W1, W1T, 1024, 2048);
  transcast<<<dim3(16, 64), dim3(256), 0, stream>>>(W2, W2T, 2048, 512);
  gemm256<1, 1><<<dim3(8, 96), dim3(512), 0, stream>>>(Xbf, W1T, b1, (void*)H, 24576, 2048, 1024);
  gemm256<0, 0><<<dim3(2, 96), dim3(512), 0, stream>>>(H, W2T, b2, (void*)E, 24576, 512, 2048);
  makeK<<<dim3(256), dim3(256), 0, stream>>>(E, Km, eta2);
  qp_kernel<<<dim3(64), dim3(256), 0, stream>>>(Km, eta2, alp);
  centers_k<<<dim3(256), dim3(128), 0, stream>>>(alp, E, ctr);
  logits_k<<<dim3(256), dim3(256), 0, stream>>>(ctr, E, out);
}